// Round 1
// baseline (8232.030 us; speedup 1.0000x reference)
//
#include <hip/hip_runtime.h>
#include <hip/hip_bf16.h>
#include <math.h>

// Problem dims (fixed by setup_inputs)
#define Bn 2
#define Sn 2048
#define Dn 1024
#define Hn 16
#define dhn 64
#define SCALE 0.125f   // 1/sqrt(64)

// ---------------------------------------------------------------------------
// Tiled f32 GEMM: C[M,N] = A[M,K] @ Bw[K,N]
// BM=BN=64, BK=16, 256 threads, 4x4 micro-tile per thread.
// MODE 0: plain row-major store to C.
// MODE 1: scatter columns into q/k/v workspaces laid out [B][H][S][dh].
// ---------------------------------------------------------------------------
template <int MODE>
__global__ __launch_bounds__(256) void gemm_f32(
    const float* __restrict__ A, const float* __restrict__ Bw,
    float* __restrict__ C, float* __restrict__ qp, float* __restrict__ kp,
    float* __restrict__ vp, int M, int N, int K) {
  __shared__ float As[16][68];  // As[k][m], padded
  __shared__ float Bs[16][68];  // Bs[k][n], padded (float4-aligned stride)
  int t = threadIdx.x;
  int tx = t & 15, ty = t >> 4;
  int bm = blockIdx.y * 64, bn = blockIdx.x * 64;
  float acc[4][4] = {};
  int arow = t >> 2, acol = (t & 3) * 4;
  int brow = t >> 4, bcol = (t & 15) * 4;
  for (int k0 = 0; k0 < K; k0 += 16) {
    float4 av = *(const float4*)(A + (size_t)(bm + arow) * K + k0 + acol);
    As[acol + 0][arow] = av.x;
    As[acol + 1][arow] = av.y;
    As[acol + 2][arow] = av.z;
    As[acol + 3][arow] = av.w;
    *(float4*)&Bs[brow][bcol] =
        *(const float4*)(Bw + (size_t)(k0 + brow) * N + bn + bcol);
    __syncthreads();
#pragma unroll
    for (int kk = 0; kk < 16; ++kk) {
      float4 a4 = *(const float4*)&As[kk][ty * 4];
      float4 b4 = *(const float4*)&Bs[kk][tx * 4];
      float a[4] = {a4.x, a4.y, a4.z, a4.w};
      float b[4] = {b4.x, b4.y, b4.z, b4.w};
#pragma unroll
      for (int i = 0; i < 4; ++i)
#pragma unroll
        for (int j = 0; j < 4; ++j) acc[i][j] += a[i] * b[j];
    }
    __syncthreads();
  }
#pragma unroll
  for (int i = 0; i < 4; ++i) {
    int rr = bm + ty * 4 + i;
#pragma unroll
    for (int j = 0; j < 4; ++j) {
      int cc = bn + tx * 4 + j;
      if (MODE == 0) {
        C[(size_t)rr * N + cc] = acc[i][j];
      } else {
        int b = rr >> 11;            // rr / S
        int s = rr & (Sn - 1);       // rr % S
        int which = cc >> 10;        // cc / D : 0=q 1=k 2=v
        int dd = cc & (Dn - 1);      // cc % D
        int hh = dd >> 6, jj = dd & 63;
        float* dst = which == 0 ? qp : (which == 1 ? kp : vp);
        dst[(((size_t)(b * Hn + hh) * Sn) + s) * dhn + jj] = acc[i][j];
      }
    }
  }
}

// ---------------------------------------------------------------------------
// NeoX RoPE applied in-place to q and k, layout [B*H][S][64].
// One thread per (row, pair) where pair i pairs elements i and i+32.
// ---------------------------------------------------------------------------
__global__ __launch_bounds__(256) void rope_kernel(float* __restrict__ q,
                                                   float* __restrict__ k) {
  int idx = blockIdx.x * 256 + threadIdx.x;  // over B*H*S*32
  int i = idx & 31;
  int row = idx >> 5;        // b*H*S + h*S + s
  int s = row & (Sn - 1);    // position
  float inv = powf(10000.0f, -(float)(2 * i) / 64.0f);
  float ang = (float)s * inv;
  float c = cosf(ang), sn = sinf(ang);
  float* qp = q + (size_t)row * dhn;
  float* kp = k + (size_t)row * dhn;
  float q0 = qp[i], q1 = qp[i + 32];
  qp[i] = q0 * c - q1 * sn;
  qp[i + 32] = q1 * c + q0 * sn;
  float k0 = kp[i], k1 = kp[i + 32];
  kp[i] = k0 * c - k1 * sn;
  kp[i + 32] = k1 * c + k0 * sn;
}

// ---------------------------------------------------------------------------
// Flash-style causal attention, f32.
// Block = 256 threads handles 64 q-rows of one (b,h). Loops over 64-wide
// K/V tiles with online softmax. Thread t: row r=t>>2, lane-group cg=t&3.
// Score phase: thread owns j in {cg+4*jj} (strided -> conflict-free Ks reads).
// PV phase:    thread owns output cols c in [cg*16, cg*16+16).
// Row stats (m,l) held redundantly in the 4 threads of a row via shfl_xor.
// ---------------------------------------------------------------------------
__global__ __launch_bounds__(256) void attn_kernel(
    const float* __restrict__ q, const float* __restrict__ k,
    const float* __restrict__ v, const int* __restrict__ mask,
    float* __restrict__ out) {
  __shared__ float Qs[64][68], Ks[64][68], Vs[64][68], Ps[64][68];
  int t = threadIdx.x;
  int r = t >> 2, cg = t & 3;
  int bh = blockIdx.y;
  int b = bh >> 4;           // bh / H
  int h = bh & (Hn - 1);
  int q0 = blockIdx.x * 64;
  const float* qptr = q + ((size_t)bh * Sn + q0) * dhn;
#pragma unroll
  for (int i = 0; i < 4; ++i) {
    int col = cg * 16 + i * 4;
    *(float4*)&Qs[r][col] = *(const float4*)(qptr + r * dhn + col);
  }
  float m_r = -INFINITY, l_r = 0.0f;
  float o[16];
#pragma unroll
  for (int i = 0; i < 16; ++i) o[i] = 0.0f;
  const int* mp = mask + b * Sn;
  int qglob = q0 + r;
  int ktiles = (q0 >> 6) + 1;
  for (int kt = 0; kt < ktiles; ++kt) {
    int k0 = kt * 64;
    const float* kptr = k + ((size_t)bh * Sn + k0) * dhn;
    const float* vptr = v + ((size_t)bh * Sn + k0) * dhn;
    __syncthreads();  // previous tile's P/V reads done; Q visible (1st iter)
#pragma unroll
    for (int i = 0; i < 4; ++i) {
      int col = cg * 16 + i * 4;
      *(float4*)&Ks[r][col] = *(const float4*)(kptr + r * dhn + col);
      *(float4*)&Vs[r][col] = *(const float4*)(vptr + r * dhn + col);
    }
    __syncthreads();
    // ---- scores: s[r][j] = q[r,:] . k[j,:], j = cg + 4*jj ----
    float sc[16];
#pragma unroll
    for (int jj = 0; jj < 16; ++jj) sc[jj] = 0.0f;
#pragma unroll
    for (int k4 = 0; k4 < 16; ++k4) {
      float4 qv = *(const float4*)&Qs[r][k4 * 4];
#pragma unroll
      for (int jj = 0; jj < 16; ++jj) {
        float4 kv = *(const float4*)&Ks[cg + 4 * jj][k4 * 4];
        sc[jj] += qv.x * kv.x + qv.y * kv.y + qv.z * kv.z + qv.w * kv.w;
      }
    }
    // ---- mask + scale + tile max ----
    float tmax = -INFINITY;
#pragma unroll
    for (int jj = 0; jj < 16; ++jj) {
      int jglob = k0 + cg + 4 * jj;
      bool dead = (jglob > qglob) || (mp[jglob] == 0);
      sc[jj] = dead ? -INFINITY : sc[jj] * SCALE;
      tmax = fmaxf(tmax, sc[jj]);
    }
    tmax = fmaxf(tmax, __shfl_xor(tmax, 1, 4));
    tmax = fmaxf(tmax, __shfl_xor(tmax, 2, 4));
    float m_new = fmaxf(m_r, tmax);
    float corr = __expf(m_r - m_new);
    float psum = 0.0f;
#pragma unroll
    for (int jj = 0; jj < 16; ++jj) {
      float p = __expf(sc[jj] - m_new);
      sc[jj] = p;
      psum += p;
    }
    psum += __shfl_xor(psum, 1, 4);
    psum += __shfl_xor(psum, 2, 4);
    l_r = l_r * corr + psum;
    m_r = m_new;
#pragma unroll
    for (int i = 0; i < 16; ++i) o[i] *= corr;
#pragma unroll
    for (int jj = 0; jj < 16; ++jj) Ps[r][cg + 4 * jj] = sc[jj];
    __syncthreads();
    // ---- PV: o[r][c] += sum_j P[r][j] * V[j][c], c = cg*16 + 0..15 ----
#pragma unroll
    for (int j4 = 0; j4 < 16; ++j4) {
      float4 pv4 = *(const float4*)&Ps[r][j4 * 4];
      float pe[4] = {pv4.x, pv4.y, pv4.z, pv4.w};
#pragma unroll
      for (int e = 0; e < 4; ++e) {
        int j = j4 * 4 + e;
#pragma unroll
        for (int i2 = 0; i2 < 4; ++i2) {
          float4 vv = *(const float4*)&Vs[j][cg * 16 + i2 * 4];
          o[i2 * 4 + 0] += pe[e] * vv.x;
          o[i2 * 4 + 1] += pe[e] * vv.y;
          o[i2 * 4 + 2] += pe[e] * vv.z;
          o[i2 * 4 + 3] += pe[e] * vv.w;
        }
      }
    }
  }
  float inv_l = 1.0f / l_r;
  float* op = out + ((size_t)(b * Sn + q0 + r)) * Dn + h * dhn + cg * 16;
#pragma unroll
  for (int i4 = 0; i4 < 4; ++i4) {
    float4 ov;
    ov.x = o[i4 * 4 + 0] * inv_l;
    ov.y = o[i4 * 4 + 1] * inv_l;
    ov.z = o[i4 * 4 + 2] * inv_l;
    ov.w = o[i4 * 4 + 3] * inv_l;
    *(float4*)&op[i4 * 4] = ov;
  }
}

// ---------------------------------------------------------------------------
extern "C" void kernel_launch(void* const* d_in, const int* in_sizes, int n_in,
                              void* d_out, int out_size, void* d_ws,
                              size_t ws_size, hipStream_t stream) {
  const float* x = (const float*)d_in[0];       // [B,S,D]
  const float* w_qkv = (const float*)d_in[1];   // [D,3D]
  const float* w_o = (const float*)d_in[2];     // [D,D]
  const int* mask = (const int*)d_in[3];        // [B,S]
  float* out = (float*)d_out;                   // [B,S,D] f32
  // Workspace layout (floats): q, k, v each [B,H,S,dh], then attn_out [B,S,D]
  float* q = (float*)d_ws;
  size_t per = (size_t)Bn * Hn * Sn * dhn;  // 4,194,304 floats
  float* k = q + per;
  float* v = k + per;
  float* ao = v + per;   // total 64 MB of f32

  // 1) QKV projection with scatter into [B,H,S,dh]
  {
    dim3 grid((3 * Dn) / 64, (Bn * Sn) / 64);
    gemm_f32<1><<<grid, 256, 0, stream>>>(x, w_qkv, nullptr, q, k, v,
                                          Bn * Sn, 3 * Dn, Dn);
  }
  // 2) RoPE on q and k
  {
    int pairs = Bn * Hn * Sn * 32;
    rope_kernel<<<pairs / 256, 256, 0, stream>>>(q, k);
  }
  // 3) causal flash attention -> attn_out [B,S,D]
  {
    dim3 grid(Sn / 64, Bn * Hn);
    attn_kernel<<<grid, 256, 0, stream>>>(q, k, v, mask, ao);
  }
  // 4) output projection
  {
    dim3 grid(Dn / 64, (Bn * Sn) / 64);
    gemm_f32<0><<<grid, 256, 0, stream>>>(ao, w_o, out, nullptr, nullptr,
                                          nullptr, Bn * Sn, Dn, Dn);
  }
}

// Round 3
// 1393.588 us; speedup vs baseline: 5.9071x; 5.9071x over previous
//
#include <hip/hip_runtime.h>
#include <hip/hip_bf16.h>
#include <math.h>

// Problem dims (fixed by setup_inputs)
#define Bn 2
#define Sn 2048
#define Dn 1024
#define Hn 16
#define dhn 64
#define SCALE 0.125f   // 1/sqrt(64)

// ---------------------------------------------------------------------------
// Tiled f32 GEMM: C[M,N] = A[M,K] @ Bw[K,N]
// BM=BN=64, BK=16, 256 threads, 4x4 micro-tile per thread.
// MODE 0: plain row-major store to C.
// MODE 1: scatter columns into q/k/v workspaces laid out [B][H][S][dh].
// ---------------------------------------------------------------------------
template <int MODE>
__global__ __launch_bounds__(256) void gemm_f32(
    const float* __restrict__ A, const float* __restrict__ Bw,
    float* __restrict__ C, float* __restrict__ qp, float* __restrict__ kp,
    float* __restrict__ vp, int M, int N, int K) {
  __shared__ float As[16][68];  // As[k][m], padded
  __shared__ float Bs[16][68];  // Bs[k][n], padded (float4-aligned stride)
  int t = threadIdx.x;
  int tx = t & 15, ty = t >> 4;
  int bm = blockIdx.y * 64, bn = blockIdx.x * 64;
  float acc[4][4] = {};
  int arow = t >> 2, acol = (t & 3) * 4;
  int brow = t >> 4, bcol = (t & 15) * 4;
  for (int k0 = 0; k0 < K; k0 += 16) {
    float4 av = *(const float4*)(A + (size_t)(bm + arow) * K + k0 + acol);
    As[acol + 0][arow] = av.x;
    As[acol + 1][arow] = av.y;
    As[acol + 2][arow] = av.z;
    As[acol + 3][arow] = av.w;
    *(float4*)&Bs[brow][bcol] =
        *(const float4*)(Bw + (size_t)(k0 + brow) * N + bn + bcol);
    __syncthreads();
#pragma unroll
    for (int kk = 0; kk < 16; ++kk) {
      float4 a4 = *(const float4*)&As[kk][ty * 4];
      float4 b4 = *(const float4*)&Bs[kk][tx * 4];
      float a[4] = {a4.x, a4.y, a4.z, a4.w};
      float b[4] = {b4.x, b4.y, b4.z, b4.w};
#pragma unroll
      for (int i = 0; i < 4; ++i)
#pragma unroll
        for (int j = 0; j < 4; ++j) acc[i][j] += a[i] * b[j];
    }
    __syncthreads();
  }
#pragma unroll
  for (int i = 0; i < 4; ++i) {
    int rr = bm + ty * 4 + i;
#pragma unroll
    for (int j = 0; j < 4; ++j) {
      int cc = bn + tx * 4 + j;
      if (MODE == 0) {
        C[(size_t)rr * N + cc] = acc[i][j];
      } else {
        int b = rr >> 11;            // rr / S
        int s = rr & (Sn - 1);       // rr % S
        int which = cc >> 10;        // cc / D : 0=q 1=k 2=v
        int dd = cc & (Dn - 1);      // cc % D
        int hh = dd >> 6, jj = dd & 63;
        float* dst = which == 0 ? qp : (which == 1 ? kp : vp);
        dst[(((size_t)(b * Hn + hh) * Sn) + s) * dhn + jj] = acc[i][j];
      }
    }
  }
}

// ---------------------------------------------------------------------------
// NeoX RoPE applied in-place to q and k, layout [B*H][S][64].
// One thread per (row, pair) where pair i pairs elements i and i+32.
// ---------------------------------------------------------------------------
__global__ __launch_bounds__(256) void rope_kernel(float* __restrict__ q,
                                                   float* __restrict__ k) {
  int idx = blockIdx.x * 256 + threadIdx.x;  // over B*H*S*32
  int i = idx & 31;
  int row = idx >> 5;        // b*H*S + h*S + s
  int s = row & (Sn - 1);    // position
  float inv = powf(10000.0f, -(float)(2 * i) / 64.0f);
  float ang = (float)s * inv;
  float c = cosf(ang), sn = sinf(ang);
  float* qp = q + (size_t)row * dhn;
  float* kp = k + (size_t)row * dhn;
  float q0 = qp[i], q1 = qp[i + 32];
  qp[i] = q0 * c - q1 * sn;
  qp[i + 32] = q1 * c + q0 * sn;
  float k0 = kp[i], k1 = kp[i + 32];
  kp[i] = k0 * c - k1 * sn;
  kp[i + 32] = k1 * c + k0 * sn;
}

// ---------------------------------------------------------------------------
// Flash-style causal attention, f32 — spill-free version.
// Block = 256 threads handles 64 q-rows of one (b,h). Loops over 64-wide
// K/V tiles with online softmax. Thread t: row r=t>>2, lane-group cg=t&3.
// Score phase: thread owns j in {cg+4*jj} (strided -> conflict-free Ks reads).
// PV phase:    thread owns output cols c in [cg*16, cg*16+16).
// Row stats (m,l) held redundantly in the 4 threads of a row via shfl_xor.
// Key change vs round 1: bounded unrolling (unroll 2 / 4) so register
// pressure stays well under the cap — round-1 full unroll spilled ~13 GB of
// scratch traffic per dispatch (WRITE_SIZE 9.5 GB vs 16 MB expected).
// ---------------------------------------------------------------------------
__global__ __launch_bounds__(256, 2) void attn_kernel(
    const float* __restrict__ q, const float* __restrict__ k,
    const float* __restrict__ v, const int* __restrict__ mask,
    float* __restrict__ out) {
  __shared__ float Qs[64][68], Ks[64][68], Vs[64][68], Ps[64][68];
  int t = threadIdx.x;
  int r = t >> 2, cg = t & 3;
  int bh = blockIdx.y;
  int b = bh >> 4;           // bh / H
  int h = bh & (Hn - 1);
  int q0 = blockIdx.x * 64;
  const float* qptr = q + ((size_t)bh * Sn + q0) * dhn;
#pragma unroll
  for (int i = 0; i < 4; ++i) {
    int col = cg * 16 + i * 4;
    *(float4*)&Qs[r][col] = *(const float4*)(qptr + r * dhn + col);
  }
  float m_r = -INFINITY, l_r = 0.0f;
  float o[16];
#pragma unroll
  for (int i = 0; i < 16; ++i) o[i] = 0.0f;
  const int* mp = mask + b * Sn;
  int qglob = q0 + r;
  int ktiles = (q0 >> 6) + 1;
  for (int kt = 0; kt < ktiles; ++kt) {
    int k0 = kt * 64;
    const float* kptr = k + ((size_t)bh * Sn + k0) * dhn;
    const float* vptr = v + ((size_t)bh * Sn + k0) * dhn;
    __syncthreads();  // previous tile's P/V reads done; Q visible (1st iter)
#pragma unroll
    for (int i = 0; i < 4; ++i) {
      int col = cg * 16 + i * 4;
      *(float4*)&Ks[r][col] = *(const float4*)(kptr + r * dhn + col);
      *(float4*)&Vs[r][col] = *(const float4*)(vptr + r * dhn + col);
    }
    __syncthreads();
    // ---- scores: s[r][j] = q[r,:] . k[j,:], j = cg + 4*jj ----
    float sc[16];
#pragma unroll
    for (int jj = 0; jj < 16; ++jj) sc[jj] = 0.0f;
#pragma unroll 2
    for (int k4 = 0; k4 < 16; ++k4) {
      float4 qv = *(const float4*)&Qs[r][k4 * 4];
#pragma unroll
      for (int jj = 0; jj < 16; ++jj) {
        float4 kv = *(const float4*)&Ks[cg + 4 * jj][k4 * 4];
        sc[jj] += qv.x * kv.x + qv.y * kv.y + qv.z * kv.z + qv.w * kv.w;
      }
    }
    // ---- mask + scale + tile max ----
    float tmax = -INFINITY;
#pragma unroll
    for (int jj = 0; jj < 16; ++jj) {
      int jglob = k0 + cg + 4 * jj;
      bool dead = (jglob > qglob) || (mp[jglob] == 0);
      sc[jj] = dead ? -INFINITY : sc[jj] * SCALE;
      tmax = fmaxf(tmax, sc[jj]);
    }
    tmax = fmaxf(tmax, __shfl_xor(tmax, 1, 4));
    tmax = fmaxf(tmax, __shfl_xor(tmax, 2, 4));
    float m_new = fmaxf(m_r, tmax);
    float corr = __expf(m_r - m_new);
    float psum = 0.0f;
#pragma unroll
    for (int jj = 0; jj < 16; ++jj) {
      float p = __expf(sc[jj] - m_new);
      sc[jj] = p;
      psum += p;
    }
    psum += __shfl_xor(psum, 1, 4);
    psum += __shfl_xor(psum, 2, 4);
    l_r = l_r * corr + psum;
    m_r = m_new;
#pragma unroll
    for (int i = 0; i < 16; ++i) o[i] *= corr;
#pragma unroll
    for (int jj = 0; jj < 16; ++jj) Ps[r][cg + 4 * jj] = sc[jj];
    __syncthreads();
    // ---- PV: o[r][c] += sum_j P[r][j] * V[j][c], c = cg*16 + 0..15 ----
#pragma unroll 4
    for (int j = 0; j < 64; ++j) {
      float p = Ps[r][j];  // same addr for the 4 threads of a row (broadcast)
#pragma unroll
      for (int i2 = 0; i2 < 4; ++i2) {
        float4 vv = *(const float4*)&Vs[j][cg * 16 + i2 * 4];
        o[i2 * 4 + 0] += p * vv.x;
        o[i2 * 4 + 1] += p * vv.y;
        o[i2 * 4 + 2] += p * vv.z;
        o[i2 * 4 + 3] += p * vv.w;
      }
    }
  }
  float inv_l = 1.0f / l_r;
  float* op = out + ((size_t)(b * Sn + q0 + r)) * Dn + h * dhn + cg * 16;
#pragma unroll
  for (int i4 = 0; i4 < 4; ++i4) {
    float4 ov;
    ov.x = o[i4 * 4 + 0] * inv_l;
    ov.y = o[i4 * 4 + 1] * inv_l;
    ov.z = o[i4 * 4 + 2] * inv_l;
    ov.w = o[i4 * 4 + 3] * inv_l;
    *(float4*)&op[i4 * 4] = ov;
  }
}

// ---------------------------------------------------------------------------
extern "C" void kernel_launch(void* const* d_in, const int* in_sizes, int n_in,
                              void* d_out, int out_size, void* d_ws,
                              size_t ws_size, hipStream_t stream) {
  const float* x = (const float*)d_in[0];       // [B,S,D]
  const float* w_qkv = (const float*)d_in[1];   // [D,3D]
  const float* w_o = (const float*)d_in[2];     // [D,D]
  const int* mask = (const int*)d_in[3];        // [B,S]
  float* out = (float*)d_out;                   // [B,S,D] f32
  // Workspace layout (floats): q, k, v each [B,H,S,dh], then attn_out [B,S,D]
  float* q = (float*)d_ws;
  size_t per = (size_t)Bn * Hn * Sn * dhn;  // 4,194,304 floats
  float* k = q + per;
  float* v = k + per;
  float* ao = v + per;   // total 64 MB of f32

  // 1) QKV projection with scatter into [B,H,S,dh]
  {
    dim3 grid((3 * Dn) / 64, (Bn * Sn) / 64);
    gemm_f32<1><<<grid, 256, 0, stream>>>(x, w_qkv, nullptr, q, k, v,
                                          Bn * Sn, 3 * Dn, Dn);
  }
  // 2) RoPE on q and k
  {
    int pairs = Bn * Hn * Sn * 32;
    rope_kernel<<<pairs / 256, 256, 0, stream>>>(q, k);
  }
  // 3) causal flash attention -> attn_out [B,S,D]
  {
    dim3 grid(Sn / 64, Bn * Hn);
    attn_kernel<<<grid, 256, 0, stream>>>(q, k, v, mask, ao);
  }
  // 4) output projection
  {
    dim3 grid(Dn / 64, (Bn * Sn) / 64);
    gemm_f32<0><<<grid, 256, 0, stream>>>(ao, w_o, out, nullptr, nullptr,
                                          nullptr, Bn * Sn, Dn, Dn);
  }
}

// Round 5
// 786.645 us; speedup vs baseline: 10.4647x; 1.7716x over previous
//
#include <hip/hip_runtime.h>
#include <hip/hip_bf16.h>
#include <math.h>

// Problem dims (fixed by setup_inputs)
#define Bn 2
#define Sn 2048
#define Dn 1024
#define Hn 16
#define dhn 64
#define SCALE 0.125f   // 1/sqrt(64)

typedef __attribute__((ext_vector_type(8))) short s16x8;  // 8 bf16 (4 VGPRs)
typedef __attribute__((ext_vector_type(4))) float f32x4;  // MFMA C/D frag
typedef __hip_bfloat16 bf16;

// ---------------------------------------------------------------------------
// Tiled f32 GEMM: C[M,N] = A[M,K] @ Bw[K,N]
// MODE 0: plain row-major store to C.
// MODE 1: scatter q,k (f32, [B][H][S][dh]) and v (bf16, same layout).
// ---------------------------------------------------------------------------
template <int MODE>
__global__ __launch_bounds__(256) void gemm_f32(
    const float* __restrict__ A, const float* __restrict__ Bw,
    float* __restrict__ C, float* __restrict__ qp, float* __restrict__ kp,
    bf16* __restrict__ vbp, int M, int N, int K) {
  __shared__ float As[16][68];  // As[k][m], padded
  __shared__ float Bs[16][68];  // Bs[k][n], padded
  int t = threadIdx.x;
  int tx = t & 15, ty = t >> 4;
  int bm = blockIdx.y * 64, bn = blockIdx.x * 64;
  float acc[4][4] = {};
  int arow = t >> 2, acol = (t & 3) * 4;
  int brow = t >> 4, bcol = (t & 15) * 4;
  for (int k0 = 0; k0 < K; k0 += 16) {
    float4 av = *(const float4*)(A + (size_t)(bm + arow) * K + k0 + acol);
    As[acol + 0][arow] = av.x;
    As[acol + 1][arow] = av.y;
    As[acol + 2][arow] = av.z;
    As[acol + 3][arow] = av.w;
    *(float4*)&Bs[brow][bcol] =
        *(const float4*)(Bw + (size_t)(k0 + brow) * N + bn + bcol);
    __syncthreads();
#pragma unroll
    for (int kk = 0; kk < 16; ++kk) {
      float4 a4 = *(const float4*)&As[kk][ty * 4];
      float4 b4 = *(const float4*)&Bs[kk][tx * 4];
      float a[4] = {a4.x, a4.y, a4.z, a4.w};
      float b[4] = {b4.x, b4.y, b4.z, b4.w};
#pragma unroll
      for (int i = 0; i < 4; ++i)
#pragma unroll
        for (int j = 0; j < 4; ++j) acc[i][j] += a[i] * b[j];
    }
    __syncthreads();
  }
#pragma unroll
  for (int i = 0; i < 4; ++i) {
    int rr = bm + ty * 4 + i;
#pragma unroll
    for (int j = 0; j < 4; ++j) {
      int cc = bn + tx * 4 + j;
      if (MODE == 0) {
        C[(size_t)rr * N + cc] = acc[i][j];
      } else {
        int b = rr >> 11;            // rr / S
        int s = rr & (Sn - 1);       // rr % S
        int which = cc >> 10;        // 0=q 1=k 2=v
        int dd = cc & (Dn - 1);
        int hh = dd >> 6, jj = dd & 63;
        size_t off = (((size_t)(b * Hn + hh) * Sn) + s) * dhn + jj;
        if (which == 0) qp[off] = acc[i][j];
        else if (which == 1) kp[off] = acc[i][j];
        else vbp[off] = __float2bfloat16(acc[i][j]);
      }
    }
  }
}

// ---------------------------------------------------------------------------
// NeoX RoPE: read f32 q,k [BH][S][64], write bf16 qb,kb same layout.
// Thread handles pair (i, i+32) of one row.
// ---------------------------------------------------------------------------
__global__ __launch_bounds__(256) void rope_bf16(
    const float* __restrict__ q, const float* __restrict__ k,
    bf16* __restrict__ qb, bf16* __restrict__ kb) {
  int idx = blockIdx.x * 256 + threadIdx.x;  // over BH*S*32
  int i = idx & 31;
  int row = idx >> 5;
  int s = row & (Sn - 1);
  float inv = powf(10000.0f, -(float)(2 * i) / 64.0f);
  float ang = (float)s * inv;
  float c = cosf(ang), sn = sinf(ang);
  const float* qp = q + (size_t)row * dhn;
  const float* kp = k + (size_t)row * dhn;
  float q0 = qp[i], q1 = qp[i + 32];
  qb[(size_t)row * dhn + i] = __float2bfloat16(q0 * c - q1 * sn);
  qb[(size_t)row * dhn + i + 32] = __float2bfloat16(q1 * c + q0 * sn);
  float k0 = kp[i], k1 = kp[i + 32];
  kb[(size_t)row * dhn + i] = __float2bfloat16(k0 * c - k1 * sn);
  kb[(size_t)row * dhn + i + 32] = __float2bfloat16(k1 * c + k0 * sn);
}

// ---------------------------------------------------------------------------
// Transpose v: vb [BH][S][64] bf16 -> vT [BH][64][S] bf16. 64x64 LDS tiles.
// ---------------------------------------------------------------------------
__global__ __launch_bounds__(256) void vtrans(const unsigned short* __restrict__ vb,
                                              unsigned short* __restrict__ vT) {
  __shared__ unsigned short L[64][72];  // [d][s], padded
  int t = threadIdx.x;
  int bh = blockIdx.y, s0 = blockIdx.x * 64;
#pragma unroll
  for (int it = 0; it < 2; ++it) {
    int sl = (t >> 3) + it * 32;
    int ch = t & 7;
    s16x8 vv = *(const s16x8*)(vb + ((size_t)bh * Sn + s0 + sl) * dhn + ch * 8);
#pragma unroll
    for (int e = 0; e < 8; ++e) L[ch * 8 + e][sl] = (unsigned short)vv[e];
  }
  __syncthreads();
#pragma unroll
  for (int it = 0; it < 2; ++it) {
    int d = (t >> 3) + it * 32;
    int sc = t & 7;
    *(s16x8*)(vT + ((size_t)(bh * dhn + d)) * Sn + s0 + sc * 8) =
        *(const s16x8*)&L[d][sc * 8];
  }
}

// ---------------------------------------------------------------------------
// MFMA flash attention (bf16 inputs, f32 accum).
// Grid: (S/64, B*H), 256 threads = 4 independent waves; wave wid handles the
// 16 q-rows [q0+wid*16, +16). No __syncthreads anywhere (per-wave P buffer).
// mfma_f32_16x16x32_bf16 layouts (guide-verified m89/m91):
//   A-frag: lane holds A[lane&15][(lane>>4)*8 + 0..7]   (16B contiguous)
//   B-frag: lane holds B[(lane>>4)*8 + 0..7][lane&15]
//   C/D:    col = lane&15, row = (lane>>4)*4 + reg
// K/V read directly from global (K/V per head = 256KB, L2-fits; m169: no LDS
// staging for cache-resident data). V is pre-transposed so B-frags of PV are
// contiguous 16B loads. P goes through padded per-wave LDS (bf16) to convert
// C-layout -> A-frag layout.
// ---------------------------------------------------------------------------
__global__ __launch_bounds__(256) void attn_mfma(
    const unsigned short* __restrict__ qb, const unsigned short* __restrict__ kb,
    const unsigned short* __restrict__ vT, const int* __restrict__ mask,
    float* __restrict__ out) {
  __shared__ bf16 P[4][16][72];  // [wave][q-row][k], +8 pad
  int t = threadIdx.x;
  int wid = t >> 6, lane = t & 63;
  int lr = lane & 15, lg = lane >> 4;
  int bh = blockIdx.y, b = bh >> 4, h = bh & (Hn - 1);
  int q0 = blockIdx.x * 64;
  int qbase = q0 + wid * 16;

  const unsigned short* qrow = qb + ((size_t)bh * Sn + qbase + lr) * dhn + lg * 8;
  s16x8 qf0 = *(const s16x8*)qrow;
  s16x8 qf1 = *(const s16x8*)(qrow + 32);

  f32x4 oc[4];
#pragma unroll
  for (int dd = 0; dd < 4; ++dd) oc[dd] = (f32x4){0.f, 0.f, 0.f, 0.f};
  float m_r[4], l_r[4];
#pragma unroll
  for (int r = 0; r < 4; ++r) { m_r[r] = -INFINITY; l_r[r] = 0.f; }

  const int* mp = mask + b * Sn;
  int ktiles = (q0 >> 6) + 1;

  for (int kt = 0; kt < ktiles; ++kt) {
    int k0 = kt * 64;
    // ---- QK^T: 4 k-subtiles of 16, K=64 split in 2 slices of 32 ----
    f32x4 pc[4];
#pragma unroll
    for (int k4 = 0; k4 < 4; ++k4) {
      const unsigned short* krow =
          kb + ((size_t)bh * Sn + k0 + k4 * 16 + lr) * dhn + lg * 8;
      s16x8 kf0 = *(const s16x8*)krow;
      s16x8 kf1 = *(const s16x8*)(krow + 32);
      f32x4 acc = (f32x4){0.f, 0.f, 0.f, 0.f};
      acc = __builtin_amdgcn_mfma_f32_16x16x32_bf16(qf0, kf0, acc, 0, 0, 0);
      acc = __builtin_amdgcn_mfma_f32_16x16x32_bf16(qf1, kf1, acc, 0, 0, 0);
      pc[k4] = acc;
    }
    // ---- online softmax (per reg r = one q-row) ----
    int mk[4];
#pragma unroll
    for (int k4 = 0; k4 < 4; ++k4) mk[k4] = mp[k0 + k4 * 16 + lr];
#pragma unroll
    for (int r = 0; r < 4; ++r) {
      int qg = qbase + lg * 4 + r;
      float sv[4];
      float tm = -INFINITY;
#pragma unroll
      for (int k4 = 0; k4 < 4; ++k4) {
        int kg = k0 + k4 * 16 + lr;
        float s = pc[k4][r] * SCALE;
        bool dead = (kg > qg) || (mk[k4] == 0);
        s = dead ? -INFINITY : s;
        sv[k4] = s;
        tm = fmaxf(tm, s);
      }
      tm = fmaxf(tm, __shfl_xor(tm, 1, 16));
      tm = fmaxf(tm, __shfl_xor(tm, 2, 16));
      tm = fmaxf(tm, __shfl_xor(tm, 4, 16));
      tm = fmaxf(tm, __shfl_xor(tm, 8, 16));
      float mn = fmaxf(m_r[r], tm);
      float corr = __expf(m_r[r] - mn);
      float ps = 0.f;
#pragma unroll
      for (int k4 = 0; k4 < 4; ++k4) {
        float p = __expf(sv[k4] - mn);
        ps += p;
        P[wid][lg * 4 + r][k4 * 16 + lr] = __float2bfloat16(p);
      }
      ps += __shfl_xor(ps, 1, 16);
      ps += __shfl_xor(ps, 2, 16);
      ps += __shfl_xor(ps, 4, 16);
      ps += __shfl_xor(ps, 8, 16);
      l_r[r] = l_r[r] * corr + ps;
      m_r[r] = mn;
#pragma unroll
      for (int dd = 0; dd < 4; ++dd) oc[dd][r] *= corr;
    }
    // ---- PV: A-frags from P (same-wave LDS round trip, no barrier) ----
    s16x8 pa0 = *(const s16x8*)&P[wid][lr][lg * 8];
    s16x8 pa1 = *(const s16x8*)&P[wid][lr][32 + lg * 8];
#pragma unroll
    for (int dd = 0; dd < 4; ++dd) {
      const unsigned short* vr =
          vT + ((size_t)(bh * dhn + dd * 16 + lr)) * Sn + k0 + lg * 8;
      s16x8 vf0 = *(const s16x8*)vr;
      s16x8 vf1 = *(const s16x8*)(vr + 32);
      oc[dd] = __builtin_amdgcn_mfma_f32_16x16x32_bf16(pa0, vf0, oc[dd], 0, 0, 0);
      oc[dd] = __builtin_amdgcn_mfma_f32_16x16x32_bf16(pa1, vf1, oc[dd], 0, 0, 0);
    }
  }
  // ---- epilogue: divide by l, write f32 [B,S,D] ----
#pragma unroll
  for (int r = 0; r < 4; ++r) {
    float invl = 1.0f / l_r[r];
    int srow = qbase + lg * 4 + r;
    float* op = out + ((size_t)(b * Sn + srow)) * Dn + h * dhn;
#pragma unroll
    for (int dd = 0; dd < 4; ++dd) op[dd * 16 + lr] = oc[dd][r] * invl;
  }
}

// ---------------------------------------------------------------------------
extern "C" void kernel_launch(void* const* d_in, const int* in_sizes, int n_in,
                              void* d_out, int out_size, void* d_ws,
                              size_t ws_size, hipStream_t stream) {
  const float* x = (const float*)d_in[0];       // [B,S,D]
  const float* w_qkv = (const float*)d_in[1];   // [D,3D]
  const float* w_o = (const float*)d_in[2];     // [D,D]
  const int* mask = (const int*)d_in[3];        // [B,S]
  float* out = (float*)d_out;                   // [B,S,D] f32

  // Workspace: exactly 64MB (proven available in rounds 1/3).
  //   [0,16M)  q f32        -> reused as ao f32 after rope consumes q
  //   [16,32M) k f32
  //   [32,40M) vb bf16
  //   [40,48M) vT bf16
  //   [48,56M) qb bf16
  //   [56,64M) kb bf16
  char* ws = (char*)d_ws;
  const size_t MB = 1024 * 1024;
  float* q = (float*)ws;
  float* k = (float*)(ws + 16 * MB);
  bf16* vb = (bf16*)(ws + 32 * MB);
  bf16* vT = (bf16*)(ws + 40 * MB);
  bf16* qb = (bf16*)(ws + 48 * MB);
  bf16* kb = (bf16*)(ws + 56 * MB);
  float* ao = q;  // overlay: q f32 is dead after rope_bf16

  // 1) QKV projection: q,k f32; v bf16, all [B,H,S,dh]
  {
    dim3 grid((3 * Dn) / 64, (Bn * Sn) / 64);
    gemm_f32<1><<<grid, 256, 0, stream>>>(x, w_qkv, nullptr, q, k, vb,
                                          Bn * Sn, 3 * Dn, Dn);
  }
  // 2) RoPE -> bf16 qb, kb
  {
    int pairs = Bn * Hn * Sn * 32;
    rope_bf16<<<pairs / 256, 256, 0, stream>>>(q, k, qb, kb);
  }
  // 3) transpose v -> vT [BH][64][S]
  {
    dim3 grid(Sn / 64, Bn * Hn);
    vtrans<<<grid, 256, 0, stream>>>((const unsigned short*)vb,
                                     (unsigned short*)vT);
  }
  // 4) MFMA flash attention -> ao [B,S,D] f32
  {
    dim3 grid(Sn / 64, Bn * Hn);
    attn_mfma<<<grid, 256, 0, stream>>>((const unsigned short*)qb,
                                        (const unsigned short*)kb,
                                        (const unsigned short*)vT, mask, ao);
  }
  // 5) output projection
  {
    dim3 grid(Dn / 64, (Bn * Sn) / 64);
    gemm_f32<0><<<grid, 256, 0, stream>>>(ao, w_o, out, nullptr, nullptr,
                                          nullptr, Bn * Sn, Dn, Dn);
  }
}

// Round 7
// 392.049 us; speedup vs baseline: 20.9975x; 2.0065x over previous
//
#include <hip/hip_runtime.h>
#include <hip/hip_bf16.h>
#include <math.h>

// Problem dims (fixed by setup_inputs)
#define Bn 2
#define Sn 2048
#define Dn 1024
#define Hn 16
#define dhn 64
#define SCALE 0.125f   // 1/sqrt(64)

typedef __attribute__((ext_vector_type(8))) short s16x8;  // 8 bf16 (4 VGPRs)
typedef __attribute__((ext_vector_type(4))) float f32x4;  // MFMA C/D frag
typedef __hip_bfloat16 bf16;

__device__ __forceinline__ unsigned short f2b(float x) {
  union { __hip_bfloat16 b; unsigned short u; } c;
  c.b = __float2bfloat16(x);
  return c.u;
}

// global_load_lds, 16B per lane. LDS dest is WAVE-UNIFORM base; HW writes
// lane l at base + l*16 (m104/m108). Global src is per-lane.
#define GLD16(gsrc, ldst)                                                  \
  __builtin_amdgcn_global_load_lds(                                        \
      (__attribute__((address_space(1))) unsigned int*)(unsigned long long)(gsrc), \
      (__attribute__((address_space(3))) unsigned int*)(ldst), 16, 0, 0)

// ---------------------------------------------------------------------------
// RoPE cos/sin tables: ctab/stab[s][i], s in [0,2048), i in [0,32).
// ---------------------------------------------------------------------------
__global__ __launch_bounds__(256) void rope_tab(float* __restrict__ ctab,
                                                float* __restrict__ stab) {
  int idx = blockIdx.x * 256 + threadIdx.x;  // 65536
  int i = idx & 31, s = idx >> 5;
  float inv = powf(10000.0f, -(float)(2 * i) / 64.0f);
  float a = (float)s * inv;
  ctab[idx] = cosf(a);
  stab[idx] = sinf(a);
}

// ---------------------------------------------------------------------------
// f32 -> bf16 elementwise (8 elems/thread, vectorized).
// ---------------------------------------------------------------------------
__global__ __launch_bounds__(256) void cvt_bf16(const float* __restrict__ in,
                                                unsigned short* __restrict__ out) {
  int idx = (blockIdx.x * 256 + threadIdx.x) * 8;
  float4 a = *(const float4*)(in + idx);
  float4 b = *(const float4*)(in + idx + 4);
  s16x8 o;
  o[0] = f2b(a.x); o[1] = f2b(a.y); o[2] = f2b(a.z); o[3] = f2b(a.w);
  o[4] = f2b(b.x); o[5] = f2b(b.y); o[6] = f2b(b.z); o[7] = f2b(b.w);
  *(s16x8*)(out + idx) = o;
}

// ---------------------------------------------------------------------------
// Convert + transpose: in [K][N] f32 -> out [N][K] bf16. 64x64 LDS tiles.
// ---------------------------------------------------------------------------
__global__ __launch_bounds__(256) void cvt_trans(const float* __restrict__ in,
                                                 unsigned short* __restrict__ out,
                                                 int K, int N) {
  __shared__ __align__(16) unsigned short L[64][72];
  int t = threadIdx.x;
  int k0 = blockIdx.y * 64, n0 = blockIdx.x * 64;
#pragma unroll
  for (int it = 0; it < 2; ++it) {
    int r = (t >> 3) + it * 32;   // k within tile
    int c = (t & 7) * 8;          // n within tile
    const float* p = in + (size_t)(k0 + r) * N + n0 + c;
    float4 a = *(const float4*)p;
    float4 b = *(const float4*)(p + 4);
    L[c + 0][r] = f2b(a.x); L[c + 1][r] = f2b(a.y);
    L[c + 2][r] = f2b(a.z); L[c + 3][r] = f2b(a.w);
    L[c + 4][r] = f2b(b.x); L[c + 5][r] = f2b(b.y);
    L[c + 6][r] = f2b(b.z); L[c + 7][r] = f2b(b.w);
  }
  __syncthreads();
#pragma unroll
  for (int it = 0; it < 2; ++it) {
    int r = (t >> 3) + it * 32;   // n row of out
    int c = (t & 7) * 8;          // k col
    *(s16x8*)(out + (size_t)(n0 + r) * K + k0 + c) = *(const s16x8*)&L[r][c];
  }
}

// ---------------------------------------------------------------------------
// MFMA GEMM (m97 structure): C[M,N] = A[M,K] @ BT[N,K]^T, all bf16 in, f32 acc.
// BM=BN=128, BK=32, 256 threads = 4 waves (2x2 of 64x64), 16 MFMA/wave/K-step,
// global_load_lds width 16, single LDS buffer, 2 barriers per K-step.
// MODE 0: C f32 row-major.
// MODE 1: QKV epilogue — RoPE (table) fused for q,k; scatter bf16 into
//         qb/kb/vb [B*H][S][64]. Pairs (i,i+32) = frags (nr, nr+2), same lane.
// ---------------------------------------------------------------------------
template <int MODE>
__global__ __launch_bounds__(256) void gemm_mfma(
    const unsigned short* __restrict__ A, const unsigned short* __restrict__ BT,
    float* __restrict__ C, bf16* __restrict__ qb, bf16* __restrict__ kb,
    bf16* __restrict__ vb, const float* __restrict__ ctab,
    const float* __restrict__ stab, int M, int N, int K) {
  __shared__ __align__(16) unsigned short As[128 * 32];
  __shared__ __align__(16) unsigned short Bs[128 * 32];
  int t = threadIdx.x;
  int wid = t >> 6, lane = t & 63;
  int lr = lane & 15, lg = lane >> 4;
  int wr = wid >> 1, wc = wid & 1;
  int bm = blockIdx.y * 128, bn = blockIdx.x * 128;

  f32x4 acc[4][4];
#pragma unroll
  for (int i = 0; i < 4; ++i)
#pragma unroll
    for (int j = 0; j < 4; ++j) acc[i][j] = (f32x4){0.f, 0.f, 0.f, 0.f};

  // Staging geometry: chunk ci = wid*2+i covers LDS rows [ci*16, ci*16+16);
  // lane l -> row ci*16 + (l>>2), col (l&3)*8 (16B).
  int ar0 = bm + wid * 32 + (lane >> 2);
  int br0 = bn + wid * 32 + (lane >> 2);
  int acx = (lane & 3) * 8;

  for (int kt = 0; kt < K; kt += 32) {
    GLD16(A + (size_t)ar0 * K + kt + acx, As + wid * 1024);
    GLD16(A + (size_t)(ar0 + 16) * K + kt + acx, As + wid * 1024 + 512);
    GLD16(BT + (size_t)br0 * K + kt + acx, Bs + wid * 1024);
    GLD16(BT + (size_t)(br0 + 16) * K + kt + acx, Bs + wid * 1024 + 512);
    __syncthreads();  // vmcnt(0) drained by compiler before barrier
    s16x8 af[4], bfr[4];
#pragma unroll
    for (int mr = 0; mr < 4; ++mr)
      af[mr] = *(const s16x8*)(As + (wr * 64 + mr * 16 + lr) * 32 + lg * 8);
#pragma unroll
    for (int nr = 0; nr < 4; ++nr)
      bfr[nr] = *(const s16x8*)(Bs + (wc * 64 + nr * 16 + lr) * 32 + lg * 8);
#pragma unroll
    for (int mr = 0; mr < 4; ++mr)
#pragma unroll
      for (int nr = 0; nr < 4; ++nr)
        acc[mr][nr] = __builtin_amdgcn_mfma_f32_16x16x32_bf16(
            af[mr], bfr[nr], acc[mr][nr], 0, 0, 0);
    __syncthreads();
  }

  if (MODE == 0) {
#pragma unroll
    for (int mr = 0; mr < 4; ++mr) {
#pragma unroll
      for (int j = 0; j < 4; ++j) {
        int rr = bm + wr * 64 + mr * 16 + lg * 4 + j;
#pragma unroll
        for (int nr = 0; nr < 4; ++nr) {
          int cc = bn + wc * 64 + nr * 16 + lr;
          C[(size_t)rr * N + cc] = acc[mr][nr][j];
        }
      }
    }
  } else {
    int wb = bn + wc * 64;     // wave col base (64-aligned, within one matrix)
    int which = wb >> 10;      // 0=q 1=k 2=v
    int h = (wb >> 6) & 15;
#pragma unroll
    for (int mr = 0; mr < 4; ++mr) {
#pragma unroll
      for (int j = 0; j < 4; ++j) {
        int rr = bm + wr * 64 + mr * 16 + lg * 4 + j;
        int b = rr >> 11, s = rr & (Sn - 1);
        size_t rowoff = (((size_t)(b * Hn + h)) * Sn + s) * dhn;
        if (which == 2) {
#pragma unroll
          for (int nr = 0; nr < 4; ++nr)
            vb[rowoff + nr * 16 + lr] = __float2bfloat16(acc[mr][nr][j]);
        } else {
          bf16* dst = (which == 0) ? qb : kb;
#pragma unroll
          for (int nr = 0; nr < 2; ++nr) {
            int dd0 = nr * 16 + lr;  // [0,32)
            float c = ctab[s * 32 + dd0];
            float sn = stab[s * 32 + dd0];
            float v0 = acc[mr][nr][j], v1 = acc[mr][nr + 2][j];
            dst[rowoff + dd0] = __float2bfloat16(v0 * c - v1 * sn);
            dst[rowoff + dd0 + 32] = __float2bfloat16(v1 * c + v0 * sn);
          }
        }
      }
    }
  }
}

// ---------------------------------------------------------------------------
// Transpose v: vb [BH][S][64] bf16 -> vT [BH][64][S] bf16. 64x64 LDS tiles.
// ---------------------------------------------------------------------------
__global__ __launch_bounds__(256) void vtrans(const unsigned short* __restrict__ vb,
                                              unsigned short* __restrict__ vT) {
  __shared__ __align__(16) unsigned short L[64][72];
  int t = threadIdx.x;
  int bh = blockIdx.y, s0 = blockIdx.x * 64;
#pragma unroll
  for (int it = 0; it < 2; ++it) {
    int sl = (t >> 3) + it * 32;
    int ch = t & 7;
    s16x8 vv = *(const s16x8*)(vb + ((size_t)bh * Sn + s0 + sl) * dhn + ch * 8);
#pragma unroll
    for (int e = 0; e < 8; ++e) L[ch * 8 + e][sl] = (unsigned short)vv[e];
  }
  __syncthreads();
#pragma unroll
  for (int it = 0; it < 2; ++it) {
    int d = (t >> 3) + it * 32;
    int sc = t & 7;
    *(s16x8*)(vT + ((size_t)(bh * dhn + d)) * Sn + s0 + sc * 8) =
        *(const s16x8*)&L[d][sc * 8];
  }
}

// ---------------------------------------------------------------------------
// MFMA flash attention (bf16 in, f32 accum, bf16 out). 4 independent waves
// per block (16 q-rows each), no __syncthreads. K/V from global (L2-fits).
// ---------------------------------------------------------------------------
__global__ __launch_bounds__(256) void attn_mfma(
    const unsigned short* __restrict__ qbp, const unsigned short* __restrict__ kbp,
    const unsigned short* __restrict__ vT, const int* __restrict__ mask,
    bf16* __restrict__ aob) {
  __shared__ __align__(16) bf16 P[4][16][72];
  int t = threadIdx.x;
  int wid = t >> 6, lane = t & 63;
  int lr = lane & 15, lg = lane >> 4;
  int bh = blockIdx.y, b = bh >> 4, h = bh & (Hn - 1);
  int q0 = blockIdx.x * 64;
  int qbase = q0 + wid * 16;

  const unsigned short* qrow = qbp + ((size_t)bh * Sn + qbase + lr) * dhn + lg * 8;
  s16x8 qf0 = *(const s16x8*)qrow;
  s16x8 qf1 = *(const s16x8*)(qrow + 32);

  f32x4 oc[4];
#pragma unroll
  for (int dd = 0; dd < 4; ++dd) oc[dd] = (f32x4){0.f, 0.f, 0.f, 0.f};
  float m_r[4], l_r[4];
#pragma unroll
  for (int r = 0; r < 4; ++r) { m_r[r] = -INFINITY; l_r[r] = 0.f; }

  const int* mp = mask + b * Sn;
  int ktiles = (q0 >> 6) + 1;

  for (int kt = 0; kt < ktiles; ++kt) {
    int k0 = kt * 64;
    f32x4 pc[4];
#pragma unroll
    for (int k4 = 0; k4 < 4; ++k4) {
      const unsigned short* krow =
          kbp + ((size_t)bh * Sn + k0 + k4 * 16 + lr) * dhn + lg * 8;
      s16x8 kf0 = *(const s16x8*)krow;
      s16x8 kf1 = *(const s16x8*)(krow + 32);
      f32x4 acc = (f32x4){0.f, 0.f, 0.f, 0.f};
      acc = __builtin_amdgcn_mfma_f32_16x16x32_bf16(qf0, kf0, acc, 0, 0, 0);
      acc = __builtin_amdgcn_mfma_f32_16x16x32_bf16(qf1, kf1, acc, 0, 0, 0);
      pc[k4] = acc;
    }
    int mk[4];
#pragma unroll
    for (int k4 = 0; k4 < 4; ++k4) mk[k4] = mp[k0 + k4 * 16 + lr];
#pragma unroll
    for (int r = 0; r < 4; ++r) {
      int qg = qbase + lg * 4 + r;
      float sv[4];
      float tm = -INFINITY;
#pragma unroll
      for (int k4 = 0; k4 < 4; ++k4) {
        int kg = k0 + k4 * 16 + lr;
        float s = pc[k4][r] * SCALE;
        bool dead = (kg > qg) || (mk[k4] == 0);
        s = dead ? -INFINITY : s;
        sv[k4] = s;
        tm = fmaxf(tm, s);
      }
      tm = fmaxf(tm, __shfl_xor(tm, 1, 16));
      tm = fmaxf(tm, __shfl_xor(tm, 2, 16));
      tm = fmaxf(tm, __shfl_xor(tm, 4, 16));
      tm = fmaxf(tm, __shfl_xor(tm, 8, 16));
      float mn = fmaxf(m_r[r], tm);
      float corr = __expf(m_r[r] - mn);
      float ps = 0.f;
#pragma unroll
      for (int k4 = 0; k4 < 4; ++k4) {
        float p = __expf(sv[k4] - mn);
        ps += p;
        P[wid][lg * 4 + r][k4 * 16 + lr] = __float2bfloat16(p);
      }
      ps += __shfl_xor(ps, 1, 16);
      ps += __shfl_xor(ps, 2, 16);
      ps += __shfl_xor(ps, 4, 16);
      ps += __shfl_xor(ps, 8, 16);
      l_r[r] = l_r[r] * corr + ps;
      m_r[r] = mn;
#pragma unroll
      for (int dd = 0; dd < 4; ++dd) oc[dd][r] *= corr;
    }
    s16x8 pa0 = *(const s16x8*)&P[wid][lr][lg * 8];
    s16x8 pa1 = *(const s16x8*)&P[wid][lr][32 + lg * 8];
#pragma unroll
    for (int dd = 0; dd < 4; ++dd) {
      const unsigned short* vr =
          vT + ((size_t)(bh * dhn + dd * 16 + lr)) * Sn + k0 + lg * 8;
      s16x8 vf0 = *(const s16x8*)vr;
      s16x8 vf1 = *(const s16x8*)(vr + 32);
      oc[dd] = __builtin_amdgcn_mfma_f32_16x16x32_bf16(pa0, vf0, oc[dd], 0, 0, 0);
      oc[dd] = __builtin_amdgcn_mfma_f32_16x16x32_bf16(pa1, vf1, oc[dd], 0, 0, 0);
    }
  }
#pragma unroll
  for (int r = 0; r < 4; ++r) {
    float invl = 1.0f / l_r[r];
    int srow = qbase + lg * 4 + r;
    bf16* op = aob + ((size_t)(b * Sn + srow)) * Dn + h * dhn;
#pragma unroll
    for (int dd = 0; dd < 4; ++dd)
      op[dd * 16 + lr] = __float2bfloat16(oc[dd][r] * invl);
  }
}

// ---------------------------------------------------------------------------
extern "C" void kernel_launch(void* const* d_in, const int* in_sizes, int n_in,
                              void* d_out, int out_size, void* d_ws,
                              size_t ws_size, hipStream_t stream) {
  const float* x = (const float*)d_in[0];       // [B,S,D]
  const float* w_qkv = (const float*)d_in[1];   // [D,3D]
  const float* w_o = (const float*)d_in[2];     // [D,D]
  const int* mask = (const int*)d_in[3];        // [B,S]
  float* out = (float*)d_out;                   // [B,S,D] f32

  // Workspace (56.5 MB total, 64 MB proven available):
  char* ws = (char*)d_ws;
  const size_t KBs = 1024;
  float* ctab = (float*)ws;                                // 256 KB
  float* stab = (float*)(ws + 256 * KBs);                  // 256 KB
  unsigned short* xb = (unsigned short*)(ws + 512 * KBs);  // 8 MB
  unsigned short* wqT = (unsigned short*)(ws + 8704 * KBs);   // 6 MB
  unsigned short* woT = (unsigned short*)(ws + 14848 * KBs);  // 2 MB
  bf16* qb = (bf16*)(ws + 16896 * KBs);                    // 8 MB
  bf16* kb = (bf16*)(ws + 25088 * KBs);                    // 8 MB
  bf16* vb = (bf16*)(ws + 33280 * KBs);                    // 8 MB
  unsigned short* vT = (unsigned short*)(ws + 41472 * KBs);   // 8 MB
  bf16* aob = (bf16*)(ws + 49664 * KBs);                   // 8 MB

  // 0) RoPE tables + bf16 conversions (+weight transposes)
  rope_tab<<<256, 256, 0, stream>>>(ctab, stab);
  cvt_bf16<<<2048, 256, 0, stream>>>(x, xb);
  { dim3 g(48, 16); cvt_trans<<<g, 256, 0, stream>>>(w_qkv, wqT, Dn, 3 * Dn); }
  { dim3 g(16, 16); cvt_trans<<<g, 256, 0, stream>>>(w_o, woT, Dn, Dn); }
  // 1) QKV projection (MFMA) + fused RoPE scatter
  { dim3 g(24, 32);
    gemm_mfma<1><<<g, 256, 0, stream>>>(xb, wqT, nullptr, qb, kb, vb, ctab,
                                        stab, Bn * Sn, 3 * Dn, Dn); }
  // 2) transpose v
  { dim3 g(Sn / 64, Bn * Hn);
    vtrans<<<g, 256, 0, stream>>>((const unsigned short*)vb,
                                  (unsigned short*)vT); }
  // 3) MFMA flash attention -> aob bf16
  { dim3 g(Sn / 64, Bn * Hn);
    attn_mfma<<<g, 256, 0, stream>>>((const unsigned short*)qb,
                                     (const unsigned short*)kb,
                                     (const unsigned short*)vT, mask, aob); }
  // 4) output projection (MFMA) -> f32 out
  { dim3 g(8, 32);
    gemm_mfma<0><<<g, 256, 0, stream>>>((const unsigned short*)aob, woT, out,
                                        nullptr, nullptr, nullptr, ctab, stab,
                                        Bn * Sn, Dn, Dn); }
}

// Round 9
// 337.545 us; speedup vs baseline: 24.3879x; 1.1615x over previous
//
#include <hip/hip_runtime.h>
#include <hip/hip_bf16.h>
#include <math.h>

// Problem dims (fixed by setup_inputs)
#define Bn 2
#define Sn 2048
#define Dn 1024
#define Hn 16
#define dhn 64
#define SCALE 0.125f   // 1/sqrt(64); folded into qb at QKV epilogue

typedef __attribute__((ext_vector_type(8))) short s16x8;  // 8 bf16 (4 VGPRs)
typedef __attribute__((ext_vector_type(4))) float f32x4;  // MFMA C/D frag
typedef __hip_bfloat16 bf16;

__device__ __forceinline__ unsigned short f2b(float x) {
  union { __hip_bfloat16 b; unsigned short u; } c;
  c.b = __float2bfloat16(x);
  return c.u;
}

// global_load_lds, 16B per lane. LDS dest is WAVE-UNIFORM base; HW writes
// lane l at base + l*16 (m104/m108). Global src is per-lane.
#define GLD16(gsrc, ldst)                                                  \
  __builtin_amdgcn_global_load_lds(                                        \
      (__attribute__((address_space(1))) unsigned int*)(unsigned long long)(gsrc), \
      (__attribute__((address_space(3))) unsigned int*)(ldst), 16, 0, 0)

// ---------------------------------------------------------------------------
// RoPE cos/sin tables: ctab/stab[s][i], s in [0,2048), i in [0,32).
// ---------------------------------------------------------------------------
__global__ __launch_bounds__(256) void rope_tab(float* __restrict__ ctab,
                                                float* __restrict__ stab) {
  int idx = blockIdx.x * 256 + threadIdx.x;  // 65536
  int i = idx & 31, s = idx >> 5;
  float inv = powf(10000.0f, -(float)(2 * i) / 64.0f);
  float a = (float)s * inv;
  ctab[idx] = cosf(a);
  stab[idx] = sinf(a);
}

// ---------------------------------------------------------------------------
// f32 -> bf16 elementwise (8 elems/thread, vectorized).
// ---------------------------------------------------------------------------
__global__ __launch_bounds__(256) void cvt_bf16(const float* __restrict__ in,
                                                unsigned short* __restrict__ out) {
  int idx = (blockIdx.x * 256 + threadIdx.x) * 8;
  float4 a = *(const float4*)(in + idx);
  float4 b = *(const float4*)(in + idx + 4);
  s16x8 o;
  o[0] = f2b(a.x); o[1] = f2b(a.y); o[2] = f2b(a.z); o[3] = f2b(a.w);
  o[4] = f2b(b.x); o[5] = f2b(b.y); o[6] = f2b(b.z); o[7] = f2b(b.w);
  *(s16x8*)(out + idx) = o;
}

// ---------------------------------------------------------------------------
// Convert + transpose: in [K][N] f32 -> out [N][K] bf16. 64x64 LDS tiles.
// ---------------------------------------------------------------------------
__global__ __launch_bounds__(256) void cvt_trans(const float* __restrict__ in,
                                                 unsigned short* __restrict__ out,
                                                 int K, int N) {
  __shared__ __align__(16) unsigned short L[64][72];
  int t = threadIdx.x;
  int k0 = blockIdx.y * 64, n0 = blockIdx.x * 64;
#pragma unroll
  for (int it = 0; it < 2; ++it) {
    int r = (t >> 3) + it * 32;   // k within tile
    int c = (t & 7) * 8;          // n within tile
    const float* p = in + (size_t)(k0 + r) * N + n0 + c;
    float4 a = *(const float4*)p;
    float4 b = *(const float4*)(p + 4);
    L[c + 0][r] = f2b(a.x); L[c + 1][r] = f2b(a.y);
    L[c + 2][r] = f2b(a.z); L[c + 3][r] = f2b(a.w);
    L[c + 4][r] = f2b(b.x); L[c + 5][r] = f2b(b.y);
    L[c + 6][r] = f2b(b.z); L[c + 7][r] = f2b(b.w);
  }
  __syncthreads();
#pragma unroll
  for (int it = 0; it < 2; ++it) {
    int r = (t >> 3) + it * 32;   // n row of out
    int c = (t & 7) * 8;          // k col
    *(s16x8*)(out + (size_t)(n0 + r) * K + k0 + c) = *(const s16x8*)&L[r][c];
  }
}

// ---------------------------------------------------------------------------
// MFMA GEMM (m97 structure): C[M,N] = A[M,K] @ BT[N,K]^T, all bf16 in, f32 acc.
// BM=BN=128, BK=32, 256 threads = 4 waves (2x2 of 64x64), 16 MFMA/wave/K-step.
// MODE 0: C f32 row-major.
// MODE 1: QKV epilogue — RoPE fused for q,k (SCALE folded into q); scatter
//         bf16 into qb/kb/vb [B*H][S][64]. Pairs (i,i+32) = frags nr, nr+2.
// ---------------------------------------------------------------------------
template <int MODE>
__global__ __launch_bounds__(256) void gemm_mfma(
    const unsigned short* __restrict__ A, const unsigned short* __restrict__ BT,
    float* __restrict__ C, bf16* __restrict__ qb, bf16* __restrict__ kb,
    bf16* __restrict__ vb, const float* __restrict__ ctab,
    const float* __restrict__ stab, int M, int N, int K) {
  __shared__ __align__(16) unsigned short As[128 * 32];
  __shared__ __align__(16) unsigned short Bs[128 * 32];
  int t = threadIdx.x;
  int wid = t >> 6, lane = t & 63;
  int lr = lane & 15, lg = lane >> 4;
  int wr = wid >> 1, wc = wid & 1;
  int bm = blockIdx.y * 128, bn = blockIdx.x * 128;

  f32x4 acc[4][4];
#pragma unroll
  for (int i = 0; i < 4; ++i)
#pragma unroll
    for (int j = 0; j < 4; ++j) acc[i][j] = (f32x4){0.f, 0.f, 0.f, 0.f};

  int ar0 = bm + wid * 32 + (lane >> 2);
  int br0 = bn + wid * 32 + (lane >> 2);
  int acx = (lane & 3) * 8;

  for (int kt = 0; kt < K; kt += 32) {
    GLD16(A + (size_t)ar0 * K + kt + acx, As + wid * 1024);
    GLD16(A + (size_t)(ar0 + 16) * K + kt + acx, As + wid * 1024 + 512);
    GLD16(BT + (size_t)br0 * K + kt + acx, Bs + wid * 1024);
    GLD16(BT + (size_t)(br0 + 16) * K + kt + acx, Bs + wid * 1024 + 512);
    __syncthreads();
    s16x8 af[4], bfr[4];
#pragma unroll
    for (int mr = 0; mr < 4; ++mr)
      af[mr] = *(const s16x8*)(As + (wr * 64 + mr * 16 + lr) * 32 + lg * 8);
#pragma unroll
    for (int nr = 0; nr < 4; ++nr)
      bfr[nr] = *(const s16x8*)(Bs + (wc * 64 + nr * 16 + lr) * 32 + lg * 8);
#pragma unroll
    for (int mr = 0; mr < 4; ++mr)
#pragma unroll
      for (int nr = 0; nr < 4; ++nr)
        acc[mr][nr] = __builtin_amdgcn_mfma_f32_16x16x32_bf16(
            af[mr], bfr[nr], acc[mr][nr], 0, 0, 0);
    __syncthreads();
  }

  if (MODE == 0) {
#pragma unroll
    for (int mr = 0; mr < 4; ++mr) {
#pragma unroll
      for (int j = 0; j < 4; ++j) {
        int rr = bm + wr * 64 + mr * 16 + lg * 4 + j;
#pragma unroll
        for (int nr = 0; nr < 4; ++nr) {
          int cc = bn + wc * 64 + nr * 16 + lr;
          C[(size_t)rr * N + cc] = acc[mr][nr][j];
        }
      }
    }
  } else {
    int wb = bn + wc * 64;     // wave col base (64-aligned, within one matrix)
    int which = wb >> 10;      // 0=q 1=k 2=v
    int h = (wb >> 6) & 15;
    float qs = (which == 0) ? SCALE : 1.0f;  // fold softmax scale into q
#pragma unroll
    for (int mr = 0; mr < 4; ++mr) {
#pragma unroll
      for (int j = 0; j < 4; ++j) {
        int rr = bm + wr * 64 + mr * 16 + lg * 4 + j;
        int b = rr >> 11, s = rr & (Sn - 1);
        size_t rowoff = (((size_t)(b * Hn + h)) * Sn + s) * dhn;
        if (which == 2) {
#pragma unroll
          for (int nr = 0; nr < 4; ++nr)
            vb[rowoff + nr * 16 + lr] = __float2bfloat16(acc[mr][nr][j]);
        } else {
          bf16* dst = (which == 0) ? qb : kb;
#pragma unroll
          for (int nr = 0; nr < 2; ++nr) {
            int dd0 = nr * 16 + lr;  // [0,32)
            float c = ctab[s * 32 + dd0];
            float sn = stab[s * 32 + dd0];
            float v0 = acc[mr][nr][j], v1 = acc[mr][nr + 2][j];
            dst[rowoff + dd0] = __float2bfloat16((v0 * c - v1 * sn) * qs);
            dst[rowoff + dd0 + 32] = __float2bfloat16((v1 * c + v0 * sn) * qs);
          }
        }
      }
    }
  }
}

// ---------------------------------------------------------------------------
// Transpose v: vb [BH][S][64] bf16 -> vT [BH][64][S] bf16. 64x64 LDS tiles.
// ---------------------------------------------------------------------------
__global__ __launch_bounds__(256) void vtrans(const unsigned short* __restrict__ vb,
                                              unsigned short* __restrict__ vT) {
  __shared__ __align__(16) unsigned short L[64][72];
  int t = threadIdx.x;
  int bh = blockIdx.y, s0 = blockIdx.x * 64;
#pragma unroll
  for (int it = 0; it < 2; ++it) {
    int sl = (t >> 3) + it * 32;
    int ch = t & 7;
    s16x8 vv = *(const s16x8*)(vb + ((size_t)bh * Sn + s0 + sl) * dhn + ch * 8);
#pragma unroll
    for (int e = 0; e < 8; ++e) L[ch * 8 + e][sl] = (unsigned short)vv[e];
  }
  __syncthreads();
#pragma unroll
  for (int it = 0; it < 2; ++it) {
    int d = (t >> 3) + it * 32;
    int sc = t & 7;
    *(s16x8*)(vT + ((size_t)(bh * dhn + d)) * Sn + s0 + sc * 8) =
        *(const s16x8*)&L[d][sc * 8];
  }
}

// ---------------------------------------------------------------------------
// MFMA flash attention, latency-optimized (round 7):
//  - 1 wave per block, 16 q-rows/wave, grid (S/16, B*H) = 4096 blocks
//    (was 1024 4-wave blocks at 22.8% occupancy — latency-bound).
//  - K-fragment register prefetch, double-buffered across k-tiles.
//  - V loads issued BEFORE softmax so softmax VALU covers their latency.
//  - SCALE pre-folded into qb.
// ---------------------------------------------------------------------------
#define ATTN_TILE(CUR, NXT)                                                    \
  {                                                                            \
    int k0 = kt * 64;                                                          \
    f32x4 pc[4];                                                               \
    _Pragma("unroll") for (int k4 = 0; k4 < 4; ++k4) {                         \
      f32x4 a = (f32x4){0.f, 0.f, 0.f, 0.f};                                   \
      a = __builtin_amdgcn_mfma_f32_16x16x32_bf16(qf0, CUR[k4 * 2], a, 0, 0, 0); \
      a = __builtin_amdgcn_mfma_f32_16x16x32_bf16(qf1, CUR[k4 * 2 + 1], a, 0, 0, 0); \
      pc[k4] = a;                                                              \
    }                                                                          \
    if (kt + 1 < ktiles) {  /* prefetch next K tile into NXT */                \
      _Pragma("unroll") for (int k4 = 0; k4 < 4; ++k4) {                       \
        const unsigned short* kr =                                             \
            kbp + ((size_t)bh * Sn + k0 + 64 + k4 * 16 + lr) * dhn + lg * 8;   \
        NXT[k4 * 2] = *(const s16x8*)kr;                                       \
        NXT[k4 * 2 + 1] = *(const s16x8*)(kr + 32);                            \
      }                                                                        \
    }                                                                          \
    s16x8 vf[8]; /* V loads early: softmax below covers their latency */       \
    _Pragma("unroll") for (int dd = 0; dd < 4; ++dd) {                         \
      const unsigned short* vr =                                               \
          vT + ((size_t)(bh * dhn + dd * 16 + lr)) * Sn + k0 + lg * 8;         \
      vf[dd * 2] = *(const s16x8*)vr;                                          \
      vf[dd * 2 + 1] = *(const s16x8*)(vr + 32);                               \
    }                                                                          \
    int mk[4];                                                                 \
    _Pragma("unroll") for (int k4 = 0; k4 < 4; ++k4)                           \
        mk[k4] = mp[k0 + k4 * 16 + lr];                                        \
    _Pragma("unroll") for (int r = 0; r < 4; ++r) {                            \
      int qg = qbase + lg * 4 + r;                                             \
      float sv[4];                                                             \
      float tm = -INFINITY;                                                    \
      _Pragma("unroll") for (int k4 = 0; k4 < 4; ++k4) {                       \
        int kg = k0 + k4 * 16 + lr;                                            \
        float s = pc[k4][r];                                                   \
        bool dead = (kg > qg) || (mk[k4] == 0);                                \
        s = dead ? -INFINITY : s;                                              \
        sv[k4] = s;                                                            \
        tm = fmaxf(tm, s);                                                     \
      }                                                                        \
      tm = fmaxf(tm, __shfl_xor(tm, 1, 16));                                   \
      tm = fmaxf(tm, __shfl_xor(tm, 2, 16));                                   \
      tm = fmaxf(tm, __shfl_xor(tm, 4, 16));                                   \
      tm = fmaxf(tm, __shfl_xor(tm, 8, 16));                                   \
      float mn = fmaxf(m_r[r], tm);                                            \
      float corr = __expf(m_r[r] - mn);                                        \
      float ps = 0.f;                                                          \
      _Pragma("unroll") for (int k4 = 0; k4 < 4; ++k4) {                       \
        float p = __expf(sv[k4] - mn);                                         \
        ps += p;                                                               \
        P[lg * 4 + r][k4 * 16 + lr] = __float2bfloat16(p);                     \
      }                                                                        \
      ps += __shfl_xor(ps, 1, 16);                                             \
      ps += __shfl_xor(ps, 2, 16);                                             \
      ps += __shfl_xor(ps, 4, 16);                                             \
      ps += __shfl_xor(ps, 8, 16);                                             \
      l_r[r] = l_r[r] * corr + ps;                                             \
      m_r[r] = mn;                                                             \
      _Pragma("unroll") for (int dd = 0; dd < 4; ++dd) oc[dd][r] *= corr;      \
    }                                                                          \
    s16x8 pa0 = *(const s16x8*)&P[lr][lg * 8];                                 \
    s16x8 pa1 = *(const s16x8*)&P[lr][32 + lg * 8];                            \
    _Pragma("unroll") for (int dd = 0; dd < 4; ++dd) {                         \
      oc[dd] = __builtin_amdgcn_mfma_f32_16x16x32_bf16(pa0, vf[dd * 2],        \
                                                       oc[dd], 0, 0, 0);       \
      oc[dd] = __builtin_amdgcn_mfma_f32_16x16x32_bf16(pa1, vf[dd * 2 + 1],    \
                                                       oc[dd], 0, 0, 0);       \
    }                                                                          \
  }

__global__ __launch_bounds__(64) void attn_mfma(
    const unsigned short* __restrict__ qbp, const unsigned short* __restrict__ kbp,
    const unsigned short* __restrict__ vT, const int* __restrict__ mask,
    bf16* __restrict__ aob) {
  __shared__ __align__(16) bf16 P[16][72];
  int lane = threadIdx.x;
  int lr = lane & 15, lg = lane >> 4;
  int bh = blockIdx.y, b = bh >> 4, h = bh & (Hn - 1);
  int qt = blockIdx.x;          // 0..127, 16 q-rows each
  int qbase = qt * 16;
  int ktiles = (qt >> 2) + 1;   // causal: k-tiles 0 .. qt/4

  const unsigned short* qrow = qbp + ((size_t)bh * Sn + qbase + lr) * dhn + lg * 8;
  s16x8 qf0 = *(const s16x8*)qrow;
  s16x8 qf1 = *(const s16x8*)(qrow + 32);

  f32x4 oc[4];
#pragma unroll
  for (int dd = 0; dd < 4; ++dd) oc[dd] = (f32x4){0.f, 0.f, 0.f, 0.f};
  float m_r[4], l_r[4];
#pragma unroll
  for (int r = 0; r < 4; ++r) { m_r[r] = -INFINITY; l_r[r] = 0.f; }

  const int* mp = mask + b * Sn;

  s16x8 kA[8], kB[8];
#pragma unroll
  for (int k4 = 0; k4 < 4; ++k4) {  // K tile 0
    const unsigned short* kr = kbp + ((size_t)bh * Sn + k4 * 16 + lr) * dhn + lg * 8;
    kA[k4 * 2] = *(const s16x8*)kr;
    kA[k4 * 2 + 1] = *(const s16x8*)(kr + 32);
  }
  int kt = 0;
  while (true) {
    ATTN_TILE(kA, kB)
    if (++kt >= ktiles) break;
    ATTN_TILE(kB, kA)
    if (++kt >= ktiles) break;
  }
#pragma unroll
  for (int r = 0; r < 4; ++r) {
    float invl = 1.0f / l_r[r];
    int srow = qbase + lg * 4 + r;
    bf16* op = aob + ((size_t)(b * Sn + srow)) * Dn + h * dhn;
#pragma unroll
    for (int dd = 0; dd < 4; ++dd)
      op[dd * 16 + lr] = __float2bfloat16(oc[dd][r] * invl);
  }
}

// ---------------------------------------------------------------------------
extern "C" void kernel_launch(void* const* d_in, const int* in_sizes, int n_in,
                              void* d_out, int out_size, void* d_ws,
                              size_t ws_size, hipStream_t stream) {
  const float* x = (const float*)d_in[0];       // [B,S,D]
  const float* w_qkv = (const float*)d_in[1];   // [D,3D]
  const float* w_o = (const float*)d_in[2];     // [D,D]
  const int* mask = (const int*)d_in[3];        // [B,S]
  float* out = (float*)d_out;                   // [B,S,D] f32

  // Workspace (56.5 MB total, 64 MB proven available):
  char* ws = (char*)d_ws;
  const size_t KBs = 1024;
  float* ctab = (float*)ws;                                // 256 KB
  float* stab = (float*)(ws + 256 * KBs);                  // 256 KB
  unsigned short* xb = (unsigned short*)(ws + 512 * KBs);  // 8 MB
  unsigned short* wqT = (unsigned short*)(ws + 8704 * KBs);   // 6 MB
  unsigned short* woT = (unsigned short*)(ws + 14848 * KBs);  // 2 MB
  bf16* qb = (bf16*)(ws + 16896 * KBs);                    // 8 MB
  bf16* kb = (bf16*)(ws + 25088 * KBs);                    // 8 MB
  bf16* vb = (bf16*)(ws + 33280 * KBs);                    // 8 MB
  unsigned short* vT = (unsigned short*)(ws + 41472 * KBs);   // 8 MB
  bf16* aob = (bf16*)(ws + 49664 * KBs);                   // 8 MB

  // 0) RoPE tables + bf16 conversions (+weight transposes)
  rope_tab<<<256, 256, 0, stream>>>(ctab, stab);
  cvt_bf16<<<2048, 256, 0, stream>>>(x, xb);
  { dim3 g(48, 16); cvt_trans<<<g, 256, 0, stream>>>(w_qkv, wqT, Dn, 3 * Dn); }
  { dim3 g(16, 16); cvt_trans<<<g, 256, 0, stream>>>(w_o, woT, Dn, Dn); }
  // 1) QKV projection (MFMA) + fused RoPE scatter (SCALE folded into qb)
  { dim3 g(24, 32);
    gemm_mfma<1><<<g, 256, 0, stream>>>(xb, wqT, nullptr, qb, kb, vb, ctab,
                                        stab, Bn * Sn, 3 * Dn, Dn); }
  // 2) transpose v
  { dim3 g(Sn / 64, Bn * Hn);
    vtrans<<<g, 256, 0, stream>>>((const unsigned short*)vb,
                                  (unsigned short*)vT); }
  // 3) MFMA flash attention (1-wave blocks) -> aob bf16
  { dim3 g(Sn / 16, Bn * Hn);
    attn_mfma<<<g, 64, 0, stream>>>((const unsigned short*)qb,
                                    (const unsigned short*)kb,
                                    (const unsigned short*)vT, mask, aob); }
  // 4) output projection (MFMA) -> f32 out
  { dim3 g(8, 32);
    gemm_mfma<0><<<g, 256, 0, stream>>>((const unsigned short*)aob, woT, out,
                                        nullptr, nullptr, nullptr, ctab, stab,
                                        Bn * Sn, Dn, Dn); }
}

// Round 11
// 313.103 us; speedup vs baseline: 26.2918x; 1.0781x over previous
//
#include <hip/hip_runtime.h>
#include <hip/hip_bf16.h>
#include <math.h>

// Problem dims (fixed by setup_inputs)
#define Bn 2
#define Sn 2048
#define Dn 1024
#define Hn 16
#define dhn 64
#define SCALE 0.125f   // 1/sqrt(64); folded into qb at QKV epilogue

typedef __attribute__((ext_vector_type(8))) short s16x8;  // 8 bf16 (4 VGPRs)
typedef __attribute__((ext_vector_type(4))) float f32x4;  // MFMA C/D frag
typedef __hip_bfloat16 bf16;

__device__ __forceinline__ unsigned short f2b(float x) {
  union { __hip_bfloat16 b; unsigned short u; } c;
  c.b = __float2bfloat16(x);
  return c.u;
}

// global_load_lds, 16B per lane. LDS dest is WAVE-UNIFORM base; HW writes
// lane l at base + l*16 (m104/m108). Global src is per-lane.
#define GLD16(gsrc, ldst)                                                  \
  __builtin_amdgcn_global_load_lds(                                        \
      (__attribute__((address_space(1))) unsigned int*)(unsigned long long)(gsrc), \
      (__attribute__((address_space(3))) unsigned int*)(ldst), 16, 0, 0)

// ---------------------------------------------------------------------------
// RoPE cos/sin tables: ctab/stab[s][i], s in [0,2048), i in [0,32).
// ---------------------------------------------------------------------------
__global__ __launch_bounds__(256) void rope_tab(float* __restrict__ ctab,
                                                float* __restrict__ stab) {
  int idx = blockIdx.x * 256 + threadIdx.x;  // 65536
  int i = idx & 31, s = idx >> 5;
  float inv = powf(10000.0f, -(float)(2 * i) / 64.0f);
  float a = (float)s * inv;
  ctab[idx] = cosf(a);
  stab[idx] = sinf(a);
}

// ---------------------------------------------------------------------------
// f32 -> bf16 elementwise (8 elems/thread, vectorized).
// ---------------------------------------------------------------------------
__global__ __launch_bounds__(256) void cvt_bf16(const float* __restrict__ in,
                                                unsigned short* __restrict__ out) {
  int idx = (blockIdx.x * 256 + threadIdx.x) * 8;
  float4 a = *(const float4*)(in + idx);
  float4 b = *(const float4*)(in + idx + 4);
  s16x8 o;
  o[0] = f2b(a.x); o[1] = f2b(a.y); o[2] = f2b(a.z); o[3] = f2b(a.w);
  o[4] = f2b(b.x); o[5] = f2b(b.y); o[6] = f2b(b.z); o[7] = f2b(b.w);
  *(s16x8*)(out + idx) = o;
}

// ---------------------------------------------------------------------------
// Convert + transpose: in [K][N] f32 -> out [N][K] bf16. 64x64 LDS tiles.
// ---------------------------------------------------------------------------
__global__ __launch_bounds__(256) void cvt_trans(const float* __restrict__ in,
                                                 unsigned short* __restrict__ out,
                                                 int K, int N) {
  __shared__ __align__(16) unsigned short L[64][72];
  int t = threadIdx.x;
  int k0 = blockIdx.y * 64, n0 = blockIdx.x * 64;
#pragma unroll
  for (int it = 0; it < 2; ++it) {
    int r = (t >> 3) + it * 32;   // k within tile
    int c = (t & 7) * 8;          // n within tile
    const float* p = in + (size_t)(k0 + r) * N + n0 + c;
    float4 a = *(const float4*)p;
    float4 b = *(const float4*)(p + 4);
    L[c + 0][r] = f2b(a.x); L[c + 1][r] = f2b(a.y);
    L[c + 2][r] = f2b(a.z); L[c + 3][r] = f2b(a.w);
    L[c + 4][r] = f2b(b.x); L[c + 5][r] = f2b(b.y);
    L[c + 6][r] = f2b(b.z); L[c + 7][r] = f2b(b.w);
  }
  __syncthreads();
#pragma unroll
  for (int it = 0; it < 2; ++it) {
    int r = (t >> 3) + it * 32;   // n row of out
    int c = (t & 7) * 8;          // k col
    *(s16x8*)(out + (size_t)(n0 + r) * K + k0 + c) = *(const s16x8*)&L[r][c];
  }
}

// ---------------------------------------------------------------------------
// MFMA GEMM (m97 structure): C[M,N] = A[M,K] @ BT[N,K]^T, all bf16 in, f32 acc.
// BM=BN=128, BK=32, 256 threads = 4 waves (2x2 of 64x64), 16 MFMA/wave/K-step.
// MODE 0: C f32 row-major.
// MODE 1: QKV epilogue — RoPE fused for q,k (SCALE folded into q); scatter
//         bf16 into qb/kb/vb [B*H][S][64]. Pairs (i,i+32) = frags nr, nr+2.
// ---------------------------------------------------------------------------
template <int MODE>
__global__ __launch_bounds__(256) void gemm_mfma(
    const unsigned short* __restrict__ A, const unsigned short* __restrict__ BT,
    float* __restrict__ C, bf16* __restrict__ qb, bf16* __restrict__ kb,
    bf16* __restrict__ vb, const float* __restrict__ ctab,
    const float* __restrict__ stab, int M, int N, int K) {
  __shared__ __align__(16) unsigned short As[128 * 32];
  __shared__ __align__(16) unsigned short Bs[128 * 32];
  int t = threadIdx.x;
  int wid = t >> 6, lane = t & 63;
  int lr = lane & 15, lg = lane >> 4;
  int wr = wid >> 1, wc = wid & 1;
  int bm = blockIdx.y * 128, bn = blockIdx.x * 128;

  f32x4 acc[4][4];
#pragma unroll
  for (int i = 0; i < 4; ++i)
#pragma unroll
    for (int j = 0; j < 4; ++j) acc[i][j] = (f32x4){0.f, 0.f, 0.f, 0.f};

  int ar0 = bm + wid * 32 + (lane >> 2);
  int br0 = bn + wid * 32 + (lane >> 2);
  int acx = (lane & 3) * 8;

  for (int kt = 0; kt < K; kt += 32) {
    GLD16(A + (size_t)ar0 * K + kt + acx, As + wid * 1024);
    GLD16(A + (size_t)(ar0 + 16) * K + kt + acx, As + wid * 1024 + 512);
    GLD16(BT + (size_t)br0 * K + kt + acx, Bs + wid * 1024);
    GLD16(BT + (size_t)(br0 + 16) * K + kt + acx, Bs + wid * 1024 + 512);
    __syncthreads();
    s16x8 af[4], bfr[4];
#pragma unroll
    for (int mr = 0; mr < 4; ++mr)
      af[mr] = *(const s16x8*)(As + (wr * 64 + mr * 16 + lr) * 32 + lg * 8);
#pragma unroll
    for (int nr = 0; nr < 4; ++nr)
      bfr[nr] = *(const s16x8*)(Bs + (wc * 64 + nr * 16 + lr) * 32 + lg * 8);
#pragma unroll
    for (int mr = 0; mr < 4; ++mr)
#pragma unroll
      for (int nr = 0; nr < 4; ++nr)
        acc[mr][nr] = __builtin_amdgcn_mfma_f32_16x16x32_bf16(
            af[mr], bfr[nr], acc[mr][nr], 0, 0, 0);
    __syncthreads();
  }

  if (MODE == 0) {
#pragma unroll
    for (int mr = 0; mr < 4; ++mr) {
#pragma unroll
      for (int j = 0; j < 4; ++j) {
        int rr = bm + wr * 64 + mr * 16 + lg * 4 + j;
#pragma unroll
        for (int nr = 0; nr < 4; ++nr) {
          int cc = bn + wc * 64 + nr * 16 + lr;
          C[(size_t)rr * N + cc] = acc[mr][nr][j];
        }
      }
    }
  } else {
    int wb = bn + wc * 64;     // wave col base (64-aligned, within one matrix)
    int which = wb >> 10;      // 0=q 1=k 2=v
    int h = (wb >> 6) & 15;
    float qs = (which == 0) ? SCALE : 1.0f;  // fold softmax scale into q
#pragma unroll
    for (int mr = 0; mr < 4; ++mr) {
#pragma unroll
      for (int j = 0; j < 4; ++j) {
        int rr = bm + wr * 64 + mr * 16 + lg * 4 + j;
        int b = rr >> 11, s = rr & (Sn - 1);
        size_t rowoff = (((size_t)(b * Hn + h)) * Sn + s) * dhn;
        if (which == 2) {
#pragma unroll
          for (int nr = 0; nr < 4; ++nr)
            vb[rowoff + nr * 16 + lr] = __float2bfloat16(acc[mr][nr][j]);
        } else {
          bf16* dst = (which == 0) ? qb : kb;
#pragma unroll
          for (int nr = 0; nr < 2; ++nr) {
            int dd0 = nr * 16 + lr;  // [0,32)
            float c = ctab[s * 32 + dd0];
            float sn = stab[s * 32 + dd0];
            float v0 = acc[mr][nr][j], v1 = acc[mr][nr + 2][j];
            dst[rowoff + dd0] = __float2bfloat16((v0 * c - v1 * sn) * qs);
            dst[rowoff + dd0 + 32] = __float2bfloat16((v1 * c + v0 * sn) * qs);
          }
        }
      }
    }
  }
}

// ---------------------------------------------------------------------------
// Transpose v: vb [BH][S][64] bf16 -> vT [BH][64][S] bf16. 64x64 LDS tiles.
// ---------------------------------------------------------------------------
__global__ __launch_bounds__(256) void vtrans(const unsigned short* __restrict__ vb,
                                              unsigned short* __restrict__ vT) {
  __shared__ __align__(16) unsigned short L[64][72];
  int t = threadIdx.x;
  int bh = blockIdx.y, s0 = blockIdx.x * 64;
#pragma unroll
  for (int it = 0; it < 2; ++it) {
    int sl = (t >> 3) + it * 32;
    int ch = t & 7;
    s16x8 vv = *(const s16x8*)(vb + ((size_t)bh * Sn + s0 + sl) * dhn + ch * 8);
#pragma unroll
    for (int e = 0; e < 8; ++e) L[ch * 8 + e][sl] = (unsigned short)vv[e];
  }
  __syncthreads();
#pragma unroll
  for (int it = 0; it < 2; ++it) {
    int d = (t >> 3) + it * 32;
    int sc = t & 7;
    *(s16x8*)(vT + ((size_t)(bh * dhn + d)) * Sn + s0 + sc * 8) =
        *(const s16x8*)&L[d][sc * 8];
  }
}

// ---------------------------------------------------------------------------
// MFMA flash attention, round 9: work-balanced 4-wave blocks.
//  - Block = 256 threads = 4 independent waves (no barriers). Wave wid
//    handles q-tile qt = blockIdx.x + wid*32 (16 q-rows). Summed ktiles per
//    block = 52..76 (vs 1..32 per-block spread in round 7) -> blocks run
//    near-uniform length, ~16 waves/CU resident incl. the tail, so one
//    wave's softmax overlaps another's MFMA/loads (m114).
//  - K-fragment register prefetch double-buffered; V loads before softmax.
//  - s_setprio(1) around MFMA clusters (T5, +4-7% attn with independent
//    waves, m191).
//  - SCALE pre-folded into qb.
// ---------------------------------------------------------------------------
#define ATTN_TILE(CUR, NXT)                                                    \
  {                                                                            \
    int k0 = kt * 64;                                                          \
    f32x4 pc[4];                                                               \
    __builtin_amdgcn_s_setprio(1);                                             \
    _Pragma("unroll") for (int k4 = 0; k4 < 4; ++k4) {                         \
      f32x4 a = (f32x4){0.f, 0.f, 0.f, 0.f};                                   \
      a = __builtin_amdgcn_mfma_f32_16x16x32_bf16(qf0, CUR[k4 * 2], a, 0, 0, 0); \
      a = __builtin_amdgcn_mfma_f32_16x16x32_bf16(qf1, CUR[k4 * 2 + 1], a, 0, 0, 0); \
      pc[k4] = a;                                                              \
    }                                                                          \
    __builtin_amdgcn_s_setprio(0);                                             \
    if (kt + 1 < ktiles) {  /* prefetch next K tile into NXT */                \
      _Pragma("unroll") for (int k4 = 0; k4 < 4; ++k4) {                       \
        const unsigned short* kr =                                             \
            kbp + ((size_t)bh * Sn + k0 + 64 + k4 * 16 + lr) * dhn + lg * 8;   \
        NXT[k4 * 2] = *(const s16x8*)kr;                                       \
        NXT[k4 * 2 + 1] = *(const s16x8*)(kr + 32);                            \
      }                                                                        \
    }                                                                          \
    s16x8 vf[8]; /* V loads early: softmax below covers their latency */       \
    _Pragma("unroll") for (int dd = 0; dd < 4; ++dd) {                         \
      const unsigned short* vr =                                               \
          vT + ((size_t)(bh * dhn + dd * 16 + lr)) * Sn + k0 + lg * 8;         \
      vf[dd * 2] = *(const s16x8*)vr;                                          \
      vf[dd * 2 + 1] = *(const s16x8*)(vr + 32);                               \
    }                                                                          \
    int mk[4];                                                                 \
    _Pragma("unroll") for (int k4 = 0; k4 < 4; ++k4)                           \
        mk[k4] = mp[k0 + k4 * 16 + lr];                                        \
    _Pragma("unroll") for (int r = 0; r < 4; ++r) {                            \
      int qg = qbase + lg * 4 + r;                                             \
      float sv[4];                                                             \
      float tm = -INFINITY;                                                    \
      _Pragma("unroll") for (int k4 = 0; k4 < 4; ++k4) {                       \
        int kg = k0 + k4 * 16 + lr;                                            \
        float s = pc[k4][r];                                                   \
        bool dead = (kg > qg) || (mk[k4] == 0);                                \
        s = dead ? -INFINITY : s;                                              \
        sv[k4] = s;                                                            \
        tm = fmaxf(tm, s);                                                     \
      }                                                                        \
      tm = fmaxf(tm, __shfl_xor(tm, 1, 16));                                   \
      tm = fmaxf(tm, __shfl_xor(tm, 2, 16));                                   \
      tm = fmaxf(tm, __shfl_xor(tm, 4, 16));                                   \
      tm = fmaxf(tm, __shfl_xor(tm, 8, 16));                                   \
      float mn = fmaxf(m_r[r], tm);                                            \
      float corr = __expf(m_r[r] - mn);                                        \
      float ps = 0.f;                                                          \
      _Pragma("unroll") for (int k4 = 0; k4 < 4; ++k4) {                       \
        float p = __expf(sv[k4] - mn);                                         \
        ps += p;                                                               \
        Pw[lg * 4 + r][k4 * 16 + lr] = __float2bfloat16(p);                    \
      }                                                                        \
      ps += __shfl_xor(ps, 1, 16);                                             \
      ps += __shfl_xor(ps, 2, 16);                                             \
      ps += __shfl_xor(ps, 4, 16);                                             \
      ps += __shfl_xor(ps, 8, 16);                                             \
      l_r[r] = l_r[r] * corr + ps;                                             \
      m_r[r] = mn;                                                             \
      _Pragma("unroll") for (int dd = 0; dd < 4; ++dd) oc[dd][r] *= corr;      \
    }                                                                          \
    s16x8 pa0 = *(const s16x8*)&Pw[lr][lg * 8];                                \
    s16x8 pa1 = *(const s16x8*)&Pw[lr][32 + lg * 8];                           \
    __builtin_amdgcn_s_setprio(1);                                             \
    _Pragma("unroll") for (int dd = 0; dd < 4; ++dd) {                         \
      oc[dd] = __builtin_amdgcn_mfma_f32_16x16x32_bf16(pa0, vf[dd * 2],        \
                                                       oc[dd], 0, 0, 0);       \
      oc[dd] = __builtin_amdgcn_mfma_f32_16x16x32_bf16(pa1, vf[dd * 2 + 1],    \
                                                       oc[dd], 0, 0, 0);       \
    }                                                                          \
    __builtin_amdgcn_s_setprio(0);                                             \
  }

__global__ __launch_bounds__(256) void attn_mfma(
    const unsigned short* __restrict__ qbp, const unsigned short* __restrict__ kbp,
    const unsigned short* __restrict__ vT, const int* __restrict__ mask,
    bf16* __restrict__ aob) {
  __shared__ __align__(16) bf16 P[4][16][72];
  int t = threadIdx.x;
  int wid = t >> 6, lane = t & 63;
  int lr = lane & 15, lg = lane >> 4;
  int bh = blockIdx.y, b = bh >> 4, h = bh & (Hn - 1);
  int qt = blockIdx.x + wid * 32;   // work-balance: waves get qt, qt+32, +64, +96
  int qbase = qt * 16;
  int ktiles = (qt >> 2) + 1;       // causal: k-tiles 0 .. qt/4
  bf16 (*Pw)[72] = P[wid];

  const unsigned short* qrow = qbp + ((size_t)bh * Sn + qbase + lr) * dhn + lg * 8;
  s16x8 qf0 = *(const s16x8*)qrow;
  s16x8 qf1 = *(const s16x8*)(qrow + 32);

  f32x4 oc[4];
#pragma unroll
  for (int dd = 0; dd < 4; ++dd) oc[dd] = (f32x4){0.f, 0.f, 0.f, 0.f};
  float m_r[4], l_r[4];
#pragma unroll
  for (int r = 0; r < 4; ++r) { m_r[r] = -INFINITY; l_r[r] = 0.f; }

  const int* mp = mask + b * Sn;

  s16x8 kA[8], kB[8];
#pragma unroll
  for (int k4 = 0; k4 < 4; ++k4) {  // K tile 0
    const unsigned short* kr = kbp + ((size_t)bh * Sn + k4 * 16 + lr) * dhn + lg * 8;
    kA[k4 * 2] = *(const s16x8*)kr;
    kA[k4 * 2 + 1] = *(const s16x8*)(kr + 32);
  }
  int kt = 0;
  while (true) {
    ATTN_TILE(kA, kB)
    if (++kt >= ktiles) break;
    ATTN_TILE(kB, kA)
    if (++kt >= ktiles) break;
  }
#pragma unroll
  for (int r = 0; r < 4; ++r) {
    float invl = 1.0f / l_r[r];
    int srow = qbase + lg * 4 + r;
    bf16* op = aob + ((size_t)(b * Sn + srow)) * Dn + h * dhn;
#pragma unroll
    for (int dd = 0; dd < 4; ++dd)
      op[dd * 16 + lr] = __float2bfloat16(oc[dd][r] * invl);
  }
}

// ---------------------------------------------------------------------------
extern "C" void kernel_launch(void* const* d_in, const int* in_sizes, int n_in,
                              void* d_out, int out_size, void* d_ws,
                              size_t ws_size, hipStream_t stream) {
  const float* x = (const float*)d_in[0];       // [B,S,D]
  const float* w_qkv = (const float*)d_in[1];   // [D,3D]
  const float* w_o = (const float*)d_in[2];     // [D,D]
  const int* mask = (const int*)d_in[3];        // [B,S]
  float* out = (float*)d_out;                   // [B,S,D] f32

  // Workspace (56.5 MB total, 64 MB proven available):
  char* ws = (char*)d_ws;
  const size_t KBs = 1024;
  float* ctab = (float*)ws;                                // 256 KB
  float* stab = (float*)(ws + 256 * KBs);                  // 256 KB
  unsigned short* xb = (unsigned short*)(ws + 512 * KBs);  // 8 MB
  unsigned short* wqT = (unsigned short*)(ws + 8704 * KBs);   // 6 MB
  unsigned short* woT = (unsigned short*)(ws + 14848 * KBs);  // 2 MB
  bf16* qb = (bf16*)(ws + 16896 * KBs);                    // 8 MB
  bf16* kb = (bf16*)(ws + 25088 * KBs);                    // 8 MB
  bf16* vb = (bf16*)(ws + 33280 * KBs);                    // 8 MB
  unsigned short* vT = (unsigned short*)(ws + 41472 * KBs);   // 8 MB
  bf16* aob = (bf16*)(ws + 49664 * KBs);                   // 8 MB

  // 0) RoPE tables + bf16 conversions (+weight transposes)
  rope_tab<<<256, 256, 0, stream>>>(ctab, stab);
  cvt_bf16<<<2048, 256, 0, stream>>>(x, xb);
  { dim3 g(48, 16); cvt_trans<<<g, 256, 0, stream>>>(w_qkv, wqT, Dn, 3 * Dn); }
  { dim3 g(16, 16); cvt_trans<<<g, 256, 0, stream>>>(w_o, woT, Dn, Dn); }
  // 1) QKV projection (MFMA) + fused RoPE scatter (SCALE folded into qb)
  { dim3 g(24, 32);
    gemm_mfma<1><<<g, 256, 0, stream>>>(xb, wqT, nullptr, qb, kb, vb, ctab,
                                        stab, Bn * Sn, 3 * Dn, Dn); }
  // 2) transpose v
  { dim3 g(Sn / 64, Bn * Hn);
    vtrans<<<g, 256, 0, stream>>>((const unsigned short*)vb,
                                  (unsigned short*)vT); }
  // 3) MFMA flash attention (work-balanced 4-wave blocks) -> aob bf16
  { dim3 g(32, Bn * Hn);
    attn_mfma<<<g, 256, 0, stream>>>((const unsigned short*)qb,
                                     (const unsigned short*)kb,
                                     (const unsigned short*)vT, mask, aob); }
  // 4) output projection (MFMA) -> f32 out
  { dim3 g(8, 32);
    gemm_mfma<0><<<g, 256, 0, stream>>>((const unsigned short*)aob, woT, out,
                                        nullptr, nullptr, nullptr, ctab, stab,
                                        Bn * Sn, Dn, Dn); }
}

// Round 13
// 232.633 us; speedup vs baseline: 35.3864x; 1.3459x over previous
//
#include <hip/hip_runtime.h>
#include <hip/hip_bf16.h>
#include <math.h>

// Problem dims (fixed by setup_inputs)
#define Bn 2
#define Sn 2048
#define Dn 1024
#define Hn 16
#define dhn 64
#define SCALE 0.125f   // 1/sqrt(64); folded into qb at QKV epilogue

typedef __attribute__((ext_vector_type(8))) short s16x8;  // 8 bf16 (4 VGPRs)
typedef __attribute__((ext_vector_type(4))) float f32x4;  // MFMA C/D frag
typedef __hip_bfloat16 bf16;

__device__ __forceinline__ unsigned short f2b(float x) {
  union { __hip_bfloat16 b; unsigned short u; } c;
  c.b = __float2bfloat16(x);
  return c.u;
}

// global_load_lds, 16B per lane. LDS dest is WAVE-UNIFORM base; HW writes
// lane l at base + l*16 (m104/m108). Global src is per-lane.
#define GLD16(gsrc, ldst)                                                  \
  __builtin_amdgcn_global_load_lds(                                        \
      (__attribute__((address_space(1))) unsigned int*)(unsigned long long)(gsrc), \
      (__attribute__((address_space(3))) unsigned int*)(ldst), 16, 0, 0)

// Swizzled ushort index into a [64][64]-bf16 LDS tile (row stride 128B):
// element (rr, byte-col cb) lives at byte rr*128 + (cb ^ ((rr&7)<<4)).
#define KSWZ(rr, cb) ((rr) * 64 + ((((cb) ^ (((rr) & 7) << 4))) >> 1))

// ---------------------------------------------------------------------------
// RoPE cos/sin tables: ctab/stab[s][i], s in [0,2048), i in [0,32).
// ---------------------------------------------------------------------------
__global__ __launch_bounds__(256) void rope_tab(float* __restrict__ ctab,
                                                float* __restrict__ stab) {
  int idx = blockIdx.x * 256 + threadIdx.x;  // 65536
  int i = idx & 31, s = idx >> 5;
  float inv = powf(10000.0f, -(float)(2 * i) / 64.0f);
  float a = (float)s * inv;
  ctab[idx] = cosf(a);
  stab[idx] = sinf(a);
}

// ---------------------------------------------------------------------------
// f32 -> bf16 elementwise (8 elems/thread, vectorized).
// ---------------------------------------------------------------------------
__global__ __launch_bounds__(256) void cvt_bf16(const float* __restrict__ in,
                                                unsigned short* __restrict__ out) {
  int idx = (blockIdx.x * 256 + threadIdx.x) * 8;
  float4 a = *(const float4*)(in + idx);
  float4 b = *(const float4*)(in + idx + 4);
  s16x8 o;
  o[0] = f2b(a.x); o[1] = f2b(a.y); o[2] = f2b(a.z); o[3] = f2b(a.w);
  o[4] = f2b(b.x); o[5] = f2b(b.y); o[6] = f2b(b.z); o[7] = f2b(b.w);
  *(s16x8*)(out + idx) = o;
}

// ---------------------------------------------------------------------------
// Convert + transpose: in [K][N] f32 -> out [N][K] bf16. 64x64 LDS tiles.
// ---------------------------------------------------------------------------
__global__ __launch_bounds__(256) void cvt_trans(const float* __restrict__ in,
                                                 unsigned short* __restrict__ out,
                                                 int K, int N) {
  __shared__ __align__(16) unsigned short L[64][72];
  int t = threadIdx.x;
  int k0 = blockIdx.y * 64, n0 = blockIdx.x * 64;
#pragma unroll
  for (int it = 0; it < 2; ++it) {
    int r = (t >> 3) + it * 32;   // k within tile
    int c = (t & 7) * 8;          // n within tile
    const float* p = in + (size_t)(k0 + r) * N + n0 + c;
    float4 a = *(const float4*)p;
    float4 b = *(const float4*)(p + 4);
    L[c + 0][r] = f2b(a.x); L[c + 1][r] = f2b(a.y);
    L[c + 2][r] = f2b(a.z); L[c + 3][r] = f2b(a.w);
    L[c + 4][r] = f2b(b.x); L[c + 5][r] = f2b(b.y);
    L[c + 6][r] = f2b(b.z); L[c + 7][r] = f2b(b.w);
  }
  __syncthreads();
#pragma unroll
  for (int it = 0; it < 2; ++it) {
    int r = (t >> 3) + it * 32;   // n row of out
    int c = (t & 7) * 8;          // k col
    *(s16x8*)(out + (size_t)(n0 + r) * K + k0 + c) = *(const s16x8*)&L[r][c];
  }
}

// ---------------------------------------------------------------------------
// MFMA GEMM (m97 structure): C[M,N] = A[M,K] @ BT[N,K]^T, all bf16 in, f32 acc.
// BM=BN=128, BK=32, 256 threads = 4 waves (2x2 of 64x64), 16 MFMA/wave/K-step.
// MODE 0: C f32 row-major.
// MODE 1: QKV epilogue — RoPE fused for q,k (SCALE folded into q); scatter
//         bf16 into qb/kb/vb [B*H][S][64]. Pairs (i,i+32) = frags nr, nr+2.
// ---------------------------------------------------------------------------
template <int MODE>
__global__ __launch_bounds__(256) void gemm_mfma(
    const unsigned short* __restrict__ A, const unsigned short* __restrict__ BT,
    float* __restrict__ C, bf16* __restrict__ qb, bf16* __restrict__ kb,
    bf16* __restrict__ vb, const float* __restrict__ ctab,
    const float* __restrict__ stab, int M, int N, int K) {
  __shared__ __align__(16) unsigned short As[128 * 32];
  __shared__ __align__(16) unsigned short Bs[128 * 32];
  int t = threadIdx.x;
  int wid = t >> 6, lane = t & 63;
  int lr = lane & 15, lg = lane >> 4;
  int wr = wid >> 1, wc = wid & 1;
  int bm = blockIdx.y * 128, bn = blockIdx.x * 128;

  f32x4 acc[4][4];
#pragma unroll
  for (int i = 0; i < 4; ++i)
#pragma unroll
    for (int j = 0; j < 4; ++j) acc[i][j] = (f32x4){0.f, 0.f, 0.f, 0.f};

  int ar0 = bm + wid * 32 + (lane >> 2);
  int br0 = bn + wid * 32 + (lane >> 2);
  int acx = (lane & 3) * 8;

  for (int kt = 0; kt < K; kt += 32) {
    GLD16(A + (size_t)ar0 * K + kt + acx, As + wid * 1024);
    GLD16(A + (size_t)(ar0 + 16) * K + kt + acx, As + wid * 1024 + 512);
    GLD16(BT + (size_t)br0 * K + kt + acx, Bs + wid * 1024);
    GLD16(BT + (size_t)(br0 + 16) * K + kt + acx, Bs + wid * 1024 + 512);
    __syncthreads();
    s16x8 af[4], bfr[4];
#pragma unroll
    for (int mr = 0; mr < 4; ++mr)
      af[mr] = *(const s16x8*)(As + (wr * 64 + mr * 16 + lr) * 32 + lg * 8);
#pragma unroll
    for (int nr = 0; nr < 4; ++nr)
      bfr[nr] = *(const s16x8*)(Bs + (wc * 64 + nr * 16 + lr) * 32 + lg * 8);
#pragma unroll
    for (int mr = 0; mr < 4; ++mr)
#pragma unroll
      for (int nr = 0; nr < 4; ++nr)
        acc[mr][nr] = __builtin_amdgcn_mfma_f32_16x16x32_bf16(
            af[mr], bfr[nr], acc[mr][nr], 0, 0, 0);
    __syncthreads();
  }

  if (MODE == 0) {
#pragma unroll
    for (int mr = 0; mr < 4; ++mr) {
#pragma unroll
      for (int j = 0; j < 4; ++j) {
        int rr = bm + wr * 64 + mr * 16 + lg * 4 + j;
#pragma unroll
        for (int nr = 0; nr < 4; ++nr) {
          int cc = bn + wc * 64 + nr * 16 + lr;
          C[(size_t)rr * N + cc] = acc[mr][nr][j];
        }
      }
    }
  } else {
    int wb = bn + wc * 64;     // wave col base (64-aligned, within one matrix)
    int which = wb >> 10;      // 0=q 1=k 2=v
    int h = (wb >> 6) & 15;
    float qs = (which == 0) ? SCALE : 1.0f;  // fold softmax scale into q
#pragma unroll
    for (int mr = 0; mr < 4; ++mr) {
#pragma unroll
      for (int j = 0; j < 4; ++j) {
        int rr = bm + wr * 64 + mr * 16 + lg * 4 + j;
        int b = rr >> 11, s = rr & (Sn - 1);
        size_t rowoff = (((size_t)(b * Hn + h)) * Sn + s) * dhn;
        if (which == 2) {
#pragma unroll
          for (int nr = 0; nr < 4; ++nr)
            vb[rowoff + nr * 16 + lr] = __float2bfloat16(acc[mr][nr][j]);
        } else {
          bf16* dst = (which == 0) ? qb : kb;
#pragma unroll
          for (int nr = 0; nr < 2; ++nr) {
            int dd0 = nr * 16 + lr;  // [0,32)
            float c = ctab[s * 32 + dd0];
            float sn = stab[s * 32 + dd0];
            float v0 = acc[mr][nr][j], v1 = acc[mr][nr + 2][j];
            dst[rowoff + dd0] = __float2bfloat16((v0 * c - v1 * sn) * qs);
            dst[rowoff + dd0 + 32] = __float2bfloat16((v1 * c + v0 * sn) * qs);
          }
        }
      }
    }
  }
}

// ---------------------------------------------------------------------------
// Transpose v: vb [BH][S][64] bf16 -> vT [BH][64][S] bf16. 64x64 LDS tiles.
// ---------------------------------------------------------------------------
__global__ __launch_bounds__(256) void vtrans(const unsigned short* __restrict__ vb,
                                              unsigned short* __restrict__ vT) {
  __shared__ __align__(16) unsigned short L[64][72];
  int t = threadIdx.x;
  int bh = blockIdx.y, s0 = blockIdx.x * 64;
#pragma unroll
  for (int it = 0; it < 2; ++it) {
    int sl = (t >> 3) + it * 32;
    int ch = t & 7;
    s16x8 vv = *(const s16x8*)(vb + ((size_t)bh * Sn + s0 + sl) * dhn + ch * 8);
#pragma unroll
    for (int e = 0; e < 8; ++e) L[ch * 8 + e][sl] = (unsigned short)vv[e];
  }
  __syncthreads();
#pragma unroll
  for (int it = 0; it < 2; ++it) {
    int d = (t >> 3) + it * 32;
    int sc = t & 7;
    *(s16x8*)(vT + ((size_t)(bh * dhn + d)) * Sn + s0 + sc * 8) =
        *(const s16x8*)&L[d][sc * 8];
  }
}

// ---------------------------------------------------------------------------
// MFMA flash attention, round 11: 8-wave LDS-staged, perfectly work-balanced.
//  - Block = 512 threads = 8 waves; processes chunk pair (c, 15-c) of 128
//    q-rows each -> every block stages exactly 34 k-tiles. Grid (8, B*H)
//    = 256 uniform blocks = 1/CU, no tail.
//  - Per k-tile: K-tile (64x64 bf16, 8KB) + vT-tile (8KB) staged ONCE into
//    LDS via global_load_lds (1 GLD16/wave each; 8x traffic cut vs per-wave
//    loads), double-buffered, ONE barrier per tile (stage next || compute).
//  - T2 XOR-swizzle per rule #21: linear LDS dest + inverse-swizzled global
//    SOURCE (scol = 8*((l&7)^(l>>3))) + swizzled read (KSWZ). Without it the
//    K/V frag reads are a 16-way bank conflict.
//  - Waves whose 16 q-rows are entirely left of the k-tile skip compute but
//    hit every barrier (barrier count is wave-uniform -> no deadlock).
//  - Softmax / P-roundtrip / PV byte-identical to the round-9-verified code.
// ---------------------------------------------------------------------------
__global__ __launch_bounds__(512) void attn_mfma8(
    const unsigned short* __restrict__ qbp, const unsigned short* __restrict__ kbp,
    const unsigned short* __restrict__ vTp, const int* __restrict__ mask,
    bf16* __restrict__ aob) {
  __shared__ __align__(16) unsigned short Kt[2][4096];  // [64][64] bf16, swizzled
  __shared__ __align__(16) unsigned short Vt[2][4096];  // vT tile [64 d][64 k]
  __shared__ __align__(16) bf16 P[8][16][72];
  int t = threadIdx.x;
  int w = t >> 6, lane = t & 63;
  int lr = lane & 15, lg = lane >> 4;
  int bh = blockIdx.y, b = bh >> 4, h = bh & (Hn - 1);
  const int* mp = mask + b * Sn;
  bf16 (*Pw)[72] = P[w];
  // Staging geometry: wave w stages tile rows [w*8, w*8+8); lane l -> LDS
  // byte w*1024 + l*16 (linear). Inverse-swizzled global column:
  int srow = w * 8 + (lane >> 3);
  int scol = 8 * ((lane & 7) ^ (lane >> 3));  // ushort elements

  for (int half = 0; half < 2; ++half) {
    int c = (half == 0) ? blockIdx.x : 15 - blockIdx.x;
    int qbase = c * 128 + w * 16;
    int qmax = qbase + 15;
    int nkt = 2 * (c + 1);  // k-tiles of 64 covering keys < (c+1)*128

    const unsigned short* qrow =
        qbp + ((size_t)bh * Sn + qbase + lr) * dhn + lg * 8;
    s16x8 qf0 = *(const s16x8*)qrow;
    s16x8 qf1 = *(const s16x8*)(qrow + 32);

    f32x4 oc[4];
#pragma unroll
    for (int dd = 0; dd < 4; ++dd) oc[dd] = (f32x4){0.f, 0.f, 0.f, 0.f};
    float m_r[4], l_r[4];
#pragma unroll
    for (int r = 0; r < 4; ++r) { m_r[r] = -INFINITY; l_r[r] = 0.f; }

    int cur = 0;
    GLD16(kbp + ((size_t)bh * Sn + srow) * dhn + scol, &Kt[0][w * 512]);
    GLD16(vTp + ((size_t)(bh * dhn) + srow) * Sn + scol, &Vt[0][w * 512]);
    __syncthreads();  // vmcnt(0) drained by compiler before s_barrier

    for (int kt = 0; kt < nkt; ++kt) {
      int k0 = kt * 64;
      if (kt + 1 < nkt) {  // stage next tile into the other buffer
        int kn = k0 + 64;
        GLD16(kbp + ((size_t)bh * Sn + kn + srow) * dhn + scol,
              &Kt[cur ^ 1][w * 512]);
        GLD16(vTp + ((size_t)(bh * dhn) + srow) * Sn + kn + scol,
              &Vt[cur ^ 1][w * 512]);
      }
      if (k0 <= qmax) {  // wave participates in this k-tile
        // ---- QK^T from LDS K-tile ----
        f32x4 pc[4];
#pragma unroll
        for (int k4 = 0; k4 < 4; ++k4) {
          int rr = k4 * 16 + lr;
          s16x8 kf0 = *(const s16x8*)&Kt[cur][KSWZ(rr, lg * 16)];
          s16x8 kf1 = *(const s16x8*)&Kt[cur][KSWZ(rr, 64 + lg * 16)];
          f32x4 a = (f32x4){0.f, 0.f, 0.f, 0.f};
          a = __builtin_amdgcn_mfma_f32_16x16x32_bf16(qf0, kf0, a, 0, 0, 0);
          a = __builtin_amdgcn_mfma_f32_16x16x32_bf16(qf1, kf1, a, 0, 0, 0);
          pc[k4] = a;
        }
        int mk[4];
#pragma unroll
        for (int k4 = 0; k4 < 4; ++k4) mk[k4] = mp[k0 + k4 * 16 + lr];
        // ---- online softmax (verified round-9 logic) ----
#pragma unroll
        for (int r = 0; r < 4; ++r) {
          int qg = qbase + lg * 4 + r;
          float sv[4];
          float tm = -INFINITY;
#pragma unroll
          for (int k4 = 0; k4 < 4; ++k4) {
            int kg = k0 + k4 * 16 + lr;
            float s = pc[k4][r];
            bool dead = (kg > qg) || (mk[k4] == 0);
            s = dead ? -INFINITY : s;
            sv[k4] = s;
            tm = fmaxf(tm, s);
          }
          tm = fmaxf(tm, __shfl_xor(tm, 1, 16));
          tm = fmaxf(tm, __shfl_xor(tm, 2, 16));
          tm = fmaxf(tm, __shfl_xor(tm, 4, 16));
          tm = fmaxf(tm, __shfl_xor(tm, 8, 16));
          float mn = fmaxf(m_r[r], tm);
          float corr = __expf(m_r[r] - mn);
          float ps = 0.f;
#pragma unroll
          for (int k4 = 0; k4 < 4; ++k4) {
            float p = __expf(sv[k4] - mn);
            ps += p;
            Pw[lg * 4 + r][k4 * 16 + lr] = __float2bfloat16(p);
          }
          ps += __shfl_xor(ps, 1, 16);
          ps += __shfl_xor(ps, 2, 16);
          ps += __shfl_xor(ps, 4, 16);
          ps += __shfl_xor(ps, 8, 16);
          l_r[r] = l_r[r] * corr + ps;
          m_r[r] = mn;
#pragma unroll
          for (int dd = 0; dd < 4; ++dd) oc[dd][r] *= corr;
        }
        // ---- PV: P A-frags (same-wave LDS roundtrip) x V-tile B-frags ----
        s16x8 pa0 = *(const s16x8*)&Pw[lr][lg * 8];
        s16x8 pa1 = *(const s16x8*)&Pw[lr][32 + lg * 8];
#pragma unroll
        for (int dd = 0; dd < 4; ++dd) {
          int rr = dd * 16 + lr;
          s16x8 vf0 = *(const s16x8*)&Vt[cur][KSWZ(rr, lg * 16)];
          s16x8 vf1 = *(const s16x8*)&Vt[cur][KSWZ(rr, 64 + lg * 16)];
          oc[dd] = __builtin_amdgcn_mfma_f32_16x16x32_bf16(pa0, vf0, oc[dd], 0, 0, 0);
          oc[dd] = __builtin_amdgcn_mfma_f32_16x16x32_bf16(pa1, vf1, oc[dd], 0, 0, 0);
        }
      }
      __syncthreads();  // next buffer staged + all reads of cur done
      cur ^= 1;
    }
    // ---- epilogue: divide by l, write bf16 ----
#pragma unroll
    for (int r = 0; r < 4; ++r) {
      float invl = 1.0f / l_r[r];
      int sr = qbase + lg * 4 + r;
      bf16* op = aob + ((size_t)(b * Sn + sr)) * Dn + h * dhn;
#pragma unroll
      for (int dd = 0; dd < 4; ++dd)
        op[dd * 16 + lr] = __float2bfloat16(oc[dd][r] * invl);
    }
  }
}

// ---------------------------------------------------------------------------
extern "C" void kernel_launch(void* const* d_in, const int* in_sizes, int n_in,
                              void* d_out, int out_size, void* d_ws,
                              size_t ws_size, hipStream_t stream) {
  const float* x = (const float*)d_in[0];       // [B,S,D]
  const float* w_qkv = (const float*)d_in[1];   // [D,3D]
  const float* w_o = (const float*)d_in[2];     // [D,D]
  const int* mask = (const int*)d_in[3];        // [B,S]
  float* out = (float*)d_out;                   // [B,S,D] f32

  // Workspace (56.5 MB total, 64 MB proven available):
  char* ws = (char*)d_ws;
  const size_t KBs = 1024;
  float* ctab = (float*)ws;                                // 256 KB
  float* stab = (float*)(ws + 256 * KBs);                  // 256 KB
  unsigned short* xb = (unsigned short*)(ws + 512 * KBs);  // 8 MB
  unsigned short* wqT = (unsigned short*)(ws + 8704 * KBs);   // 6 MB
  unsigned short* woT = (unsigned short*)(ws + 14848 * KBs);  // 2 MB
  bf16* qb = (bf16*)(ws + 16896 * KBs);                    // 8 MB
  bf16* kb = (bf16*)(ws + 25088 * KBs);                    // 8 MB
  bf16* vb = (bf16*)(ws + 33280 * KBs);                    // 8 MB
  unsigned short* vT = (unsigned short*)(ws + 41472 * KBs);   // 8 MB
  bf16* aob = (bf16*)(ws + 49664 * KBs);                   // 8 MB

  // 0) RoPE tables + bf16 conversions (+weight transposes)
  rope_tab<<<256, 256, 0, stream>>>(ctab, stab);
  cvt_bf16<<<2048, 256, 0, stream>>>(x, xb);
  { dim3 g(48, 16); cvt_trans<<<g, 256, 0, stream>>>(w_qkv, wqT, Dn, 3 * Dn); }
  { dim3 g(16, 16); cvt_trans<<<g, 256, 0, stream>>>(w_o, woT, Dn, Dn); }
  // 1) QKV projection (MFMA) + fused RoPE scatter (SCALE folded into qb)
  { dim3 g(24, 32);
    gemm_mfma<1><<<g, 256, 0, stream>>>(xb, wqT, nullptr, qb, kb, vb, ctab,
                                        stab, Bn * Sn, 3 * Dn, Dn); }
  // 2) transpose v
  { dim3 g(Sn / 64, Bn * Hn);
    vtrans<<<g, 256, 0, stream>>>((const unsigned short*)vb,
                                  (unsigned short*)vT); }
  // 3) MFMA flash attention (8-wave LDS-staged, balanced) -> aob bf16
  { dim3 g(8, Bn * Hn);
    attn_mfma8<<<g, 512, 0, stream>>>((const unsigned short*)qb,
                                      (const unsigned short*)kb,
                                      (const unsigned short*)vT, mask, aob); }
  // 4) output projection (MFMA) -> f32 out
  { dim3 g(8, 32);
    gemm_mfma<0><<<g, 256, 0, stream>>>((const unsigned short*)aob, woT, out,
                                        nullptr, nullptr, nullptr, ctab, stab,
                                        Bn * Sn, Dn, Dn); }
}